// Round 2
// baseline (1338.558 us; speedup 1.0000x reference)
//
#include <hip/hip_runtime.h>
#include <hip/hip_bf16.h>
#include <math.h>

#define NB 2
#define NS 2048
#define ND 768
#define NH 12
#define HD 64
#define WIN 128
#define N_QKV 2304
#define QKN (NB * NH * NS * HD)   // 3145728 elements per Q/K/V/CTX buffer

// ---------------------------------------------------------------------------
// Kernel 1: qkv = x @ Wqkv + bqkv, fused RoPE on q,k.
// Writes Q,K,V as fp32 [B][H][S][HD].
// Block: 256 threads, 64x64 output tile, 4x4 per thread, K-tile 16.
// Column quads are 4-aligned -> RoPE (even,odd) pairs live in one thread.
// ---------------------------------------------------------------------------
__global__ __launch_bounds__(256) void qkv_rope_kernel(
    const float* __restrict__ x,      // [4096][768]
    const float* __restrict__ Wqkv,   // [768][2304]
    const float* __restrict__ bqkv,   // [2304]
    const int* __restrict__ layer_idx_p,
    float* __restrict__ Qo, float* __restrict__ Ko, float* __restrict__ Vo)
{
  __shared__ float As[16][66];
  __shared__ float Bs[16][66];
  const int bn = blockIdx.x * 64;
  const int bm = blockIdx.y * 64;
  const int tid = threadIdx.x;
  const int tm = tid >> 4;   // 0..15
  const int tn = tid & 15;   // 0..15

  float acc[4][4] = {};

  for (int k0 = 0; k0 < ND; k0 += 16) {
    // A tile: 64 rows x 16 k
    for (int idx = tid; idx < 1024; idx += 256) {
      int r = idx >> 4, kk = idx & 15;
      As[kk][r] = x[(size_t)(bm + r) * ND + (k0 + kk)];
    }
    // B tile: 16 k x 64 cols
    for (int idx = tid; idx < 1024; idx += 256) {
      int kk = idx >> 6, c = idx & 63;
      Bs[kk][c] = Wqkv[(size_t)(k0 + kk) * N_QKV + (bn + c)];
    }
    __syncthreads();
#pragma unroll
    for (int kk = 0; kk < 16; ++kk) {
      float a[4], b[4];
#pragma unroll
      for (int r = 0; r < 4; ++r) a[r] = As[kk][tm * 4 + r];
#pragma unroll
      for (int c = 0; c < 4; ++c) b[c] = Bs[kk][tn * 4 + c];
#pragma unroll
      for (int r = 0; r < 4; ++r)
#pragma unroll
        for (int c = 0; c < 4; ++c) acc[r][c] += a[r] * b[c];
    }
    __syncthreads();
  }

  const int li = *layer_idx_p;
  const bool is_global = (li % 3) == 0;
  const float theta = is_global ? 160000.0f : 10000.0f;

#pragma unroll
  for (int r = 0; r < 4; ++r) {
    const int m = bm + tm * 4 + r;       // 0..4095
    const int s = m & (NS - 1);          // seq pos
    const int bidx = m >> 11;            // batch
#pragma unroll
    for (int cc = 0; cc < 4; cc += 2) {
      const int n = bn + tn * 4 + cc;    // even
      const int which = n / ND;          // 0=q 1=k 2=v
      const int hd = n - which * ND;     // 0..767
      const int h = hd >> 6;
      const int d = hd & 63;             // even
      float e = acc[r][cc]     + bqkv[n];
      float o = acc[r][cc + 1] + bqkv[n + 1];
      if (which < 2) {
        // pair index t = d/2; freq = theta^{-(2t)/64}; ang = s * freq
        const float freq = powf(theta, -(float)d / 64.0f);  // d == 2t
        const float ang = (float)s * freq;
        float sn, cs;
        sincosf(ang, &sn, &cs);
        const float re = e * cs - o * sn;
        const float ro = o * cs + e * sn;
        e = re; o = ro;
      }
      float* dst = (which == 0) ? Qo : ((which == 1) ? Ko : Vo);
      const size_t off = (((size_t)(bidx * NH + h)) * NS + s) * HD + d;
      dst[off]     = e;
      dst[off + 1] = o;
    }
  }
}

// ---------------------------------------------------------------------------
// Kernel 2: banded (or full, if global layer) attention, online softmax.
// One wave per query; lane = head-dim element. 4 waves / block.
// Writes CTX fp32 as [B][S][H][HD] == [4096][768].
// ---------------------------------------------------------------------------
__global__ __launch_bounds__(256) void attn_kernel(
    const float* __restrict__ Q, const float* __restrict__ K,
    const float* __restrict__ V, float* __restrict__ CTX,
    const int* __restrict__ layer_idx_p)
{
  const int lane = threadIdx.x & 63;
  const int w = threadIdx.x >> 6;
  const int qidx = blockIdx.x * 4 + w;          // 0 .. B*H*S-1
  const int b = qidx / (NH * NS);
  const int rem = qidx - b * (NH * NS);
  const int h = rem / NS;
  const int i = rem - h * NS;

  const bool is_global = ((*layer_idx_p) % 3) == 0;
  const int j0 = is_global ? 0 : max(0, i - WIN);
  const int j1 = is_global ? (NS - 1) : min(NS - 1, i + WIN);

  const size_t base = ((size_t)(b * NH + h)) * NS * HD;
  const float qd = Q[base + (size_t)i * HD + lane];

  float m = -INFINITY, l = 0.0f, o = 0.0f;
  for (int j = j0; j <= j1; ++j) {
    float p = qd * K[base + (size_t)j * HD + lane];
#pragma unroll
    for (int off = 1; off < 64; off <<= 1) p += __shfl_xor(p, off);
    const float sc = p * 0.125f;                // 1/sqrt(64)
    const float mn = fmaxf(m, sc);
    const float corr = expf(m - mn);            // expf(-inf)=0 on first iter
    const float e = expf(sc - mn);
    const float vd = V[base + (size_t)j * HD + lane];
    l = l * corr + e;
    o = o * corr + e * vd;
    m = mn;
  }
  CTX[(((size_t)(b * NS + i)) * NH + h) * HD + lane] = o / l;
}

// ---------------------------------------------------------------------------
// Kernel 3: out = CTX @ Wout + bout  -> fp32
// ---------------------------------------------------------------------------
__global__ __launch_bounds__(256) void out_proj_kernel(
    const float* __restrict__ CTX,             // [4096][768] fp32
    const float* __restrict__ Wout,            // [768][768]
    const float* __restrict__ bout,            // [768]
    float* __restrict__ out)                   // [4096][768]
{
  __shared__ float As[16][66];
  __shared__ float Bs[16][66];
  const int bn = blockIdx.x * 64;
  const int bm = blockIdx.y * 64;
  const int tid = threadIdx.x;
  const int tm = tid >> 4;
  const int tn = tid & 15;

  float acc[4][4] = {};

  for (int k0 = 0; k0 < ND; k0 += 16) {
    for (int idx = tid; idx < 1024; idx += 256) {
      int r = idx >> 4, kk = idx & 15;
      As[kk][r] = CTX[(size_t)(bm + r) * ND + (k0 + kk)];
    }
    for (int idx = tid; idx < 1024; idx += 256) {
      int kk = idx >> 6, c = idx & 63;
      Bs[kk][c] = Wout[(size_t)(k0 + kk) * ND + (bn + c)];
    }
    __syncthreads();
#pragma unroll
    for (int kk = 0; kk < 16; ++kk) {
      float a[4], b[4];
#pragma unroll
      for (int r = 0; r < 4; ++r) a[r] = As[kk][tm * 4 + r];
#pragma unroll
      for (int c = 0; c < 4; ++c) b[c] = Bs[kk][tn * 4 + c];
#pragma unroll
      for (int r = 0; r < 4; ++r)
#pragma unroll
        for (int c = 0; c < 4; ++c) acc[r][c] += a[r] * b[c];
    }
    __syncthreads();
  }

#pragma unroll
  for (int r = 0; r < 4; ++r) {
    const int m = bm + tm * 4 + r;
#pragma unroll
    for (int c = 0; c < 4; ++c) {
      const int n = bn + tn * 4 + c;
      out[(size_t)m * ND + n] = acc[r][c] + bout[n];
    }
  }
}

// ---------------------------------------------------------------------------
extern "C" void kernel_launch(void* const* d_in, const int* in_sizes, int n_in,
                              void* d_out, int out_size, void* d_ws, size_t ws_size,
                              hipStream_t stream) {
  const float* x    = (const float*)d_in[0];
  const float* Wqkv = (const float*)d_in[1];
  const float* bqkv = (const float*)d_in[2];
  const float* Wout = (const float*)d_in[3];
  const float* bout = (const float*)d_in[4];
  const int* layer_idx = (const int*)d_in[5];

  float* ws  = (float*)d_ws;
  float* Q   = ws;
  float* K   = ws + (size_t)QKN;
  float* V   = ws + (size_t)2 * QKN;
  float* CTX = ws + (size_t)3 * QKN;
  // requires ws_size >= 4 * 3145728 * 4 = 50331648 bytes

  dim3 g1(N_QKV / 64, (NB * NS) / 64);   // (36, 64)
  qkv_rope_kernel<<<g1, 256, 0, stream>>>(x, Wqkv, bqkv, layer_idx, Q, K, V);

  const int nquery = NB * NH * NS;       // 49152
  attn_kernel<<<nquery / 4, 256, 0, stream>>>(Q, K, V, CTX, layer_idx);

  dim3 g3(ND / 64, (NB * NS) / 64);      // (12, 64)
  out_proj_kernel<<<g3, 256, 0, stream>>>(CTX, Wout, bout, (float*)d_out);
}

// Round 3
// 513.751 us; speedup vs baseline: 2.6055x; 2.6055x over previous
//
#include <hip/hip_runtime.h>
#include <hip/hip_bf16.h>
#include <math.h>

#define NB 2
#define NS 2048
#define ND 768
#define NH 12
#define HD 64
#define WIN 128
#define N_QKV 2304
#define QKN (NB * NH * NS * HD)   // 3145728 elements per Q/K/V buffer

typedef __attribute__((ext_vector_type(8))) short short8;
typedef __attribute__((ext_vector_type(4))) short short4v;
typedef __attribute__((ext_vector_type(4))) float float4v;

static __device__ inline short f2bf(float f) {
  __hip_bfloat16 h = __float2bfloat16(f);
  short s;
  __builtin_memcpy(&s, &h, 2);
  return s;
}

// ---------------------------------------------------------------------------
// Kernel 1: qkv = x @ Wqkv + bqkv, fused RoPE on q,k.
// Outputs: Q,K bf16 [b][h][s][64]; V bf16 TRANSPOSED [b][h][64][s].
// ---------------------------------------------------------------------------
__global__ __launch_bounds__(256) void qkv_rope_kernel(
    const float* __restrict__ x,      // [4096][768]
    const float* __restrict__ Wqkv,   // [768][2304]
    const float* __restrict__ bqkv,   // [2304]
    const int* __restrict__ layer_idx_p,
    short* __restrict__ Qb, short* __restrict__ Kb, short* __restrict__ VT)
{
  __shared__ float As[16][66];
  __shared__ float Bs[16][66];
  const int bn = blockIdx.x * 64;
  const int bm = blockIdx.y * 64;
  const int tid = threadIdx.x;
  const int tm = tid >> 4;   // 0..15
  const int tn = tid & 15;   // 0..15

  float acc[4][4] = {};

  for (int k0 = 0; k0 < ND; k0 += 16) {
    for (int idx = tid; idx < 1024; idx += 256) {
      int r = idx >> 4, kk = idx & 15;
      As[kk][r] = x[(size_t)(bm + r) * ND + (k0 + kk)];
    }
    for (int idx = tid; idx < 1024; idx += 256) {
      int kk = idx >> 6, c = idx & 63;
      Bs[kk][c] = Wqkv[(size_t)(k0 + kk) * N_QKV + (bn + c)];
    }
    __syncthreads();
#pragma unroll
    for (int kk = 0; kk < 16; ++kk) {
      float a[4], b[4];
#pragma unroll
      for (int r = 0; r < 4; ++r) a[r] = As[kk][tm * 4 + r];
#pragma unroll
      for (int c = 0; c < 4; ++c) b[c] = Bs[kk][tn * 4 + c];
#pragma unroll
      for (int r = 0; r < 4; ++r)
#pragma unroll
        for (int c = 0; c < 4; ++c) acc[r][c] += a[r] * b[c];
    }
    __syncthreads();
  }

  const int which = bn / ND;              // uniform per block: 0=q 1=k 2=v
  const int m0 = bm + tm * 4;             // 4 consecutive rows, same batch
  const int bidx = m0 >> 11;
  const int s0 = m0 & (NS - 1);

  if (which == 2) {
    // V path: no RoPE; write transposed VT[bh][d][s] as short4 over rows.
#pragma unroll
    for (int cc = 0; cc < 4; ++cc) {
      const int n = bn + tn * 4 + cc;
      const int hd = n - 2 * ND;
      const int h = hd >> 6;
      const int d = hd & 63;
      const float bias = bqkv[n];
      short4v v4;
#pragma unroll
      for (int r = 0; r < 4; ++r) v4[r] = f2bf(acc[r][cc] + bias);
      *(short4v*)(VT + ((size_t)(bidx * NH + h) * HD + d) * NS + s0) = v4;
    }
  } else {
    const int li = *layer_idx_p;
    const bool is_global = (li % 3) == 0;
    const float theta = is_global ? 160000.0f : 10000.0f;
    short* dst = (which == 0) ? Qb : Kb;
#pragma unroll
    for (int r = 0; r < 4; ++r) {
      const int s = s0 + r;
#pragma unroll
      for (int cc = 0; cc < 4; cc += 2) {
        const int n = bn + tn * 4 + cc;     // even
        const int hd = n - which * ND;
        const int h = hd >> 6;
        const int d = hd & 63;              // even
        float e = acc[r][cc]     + bqkv[n];
        float o = acc[r][cc + 1] + bqkv[n + 1];
        const float freq = powf(theta, -(float)d / 64.0f);
        const float ang = (float)s * freq;
        float sn, cs;
        sincosf(ang, &sn, &cs);
        const float re = e * cs - o * sn;
        const float ro = o * cs + e * sn;
        ushort2 pk;
        pk.x = (unsigned short)f2bf(re);
        pk.y = (unsigned short)f2bf(ro);
        *(ushort2*)(dst + ((size_t)(bidx * NH + h) * NS + s) * HD + d) = pk;
      }
    }
  }
}

// ---------------------------------------------------------------------------
// Kernel 2: MFMA banded flash attention.
// Wave handles 16 queries of one (b,h). S^T = K·Q^T via 16x16x32 bf16 MFMA
// (C layout: col=query=lane&15, row=key=quad*4+reg). Online softmax state is
// per-lane (column). P^T re-enters PV as the B operand via 16 ds_bpermutes.
// O^T = V^T · P^T accumulated in 4 C-frags. No LDS, no barriers.
// ---------------------------------------------------------------------------
__global__ __launch_bounds__(256) void attn_mfma_kernel(
    const short* __restrict__ Qb, const short* __restrict__ Kb,
    const short* __restrict__ VT, float* __restrict__ CTX,
    const int* __restrict__ layer_idx_p)
{
  const int lane = threadIdx.x & 63;
  const int wv = threadIdx.x >> 6;
  const int c = lane & 15;        // column: query / d-within-chunk
  const int g = lane >> 4;        // quad
  const int bh = blockIdx.x >> 5;            // 0..23
  const int qt = blockIdx.x & 31;
  const int b = bh / NH;
  const int h = bh - b * NH;
  const int q0 = qt * 64 + wv * 16;
  const bool is_global = ((*layer_idx_p) % 3) == 0;
  const size_t base = (size_t)bh * NS * HD;  // bf16 elements

  // Q B-frags (B[k=d][n=q]): lane reads Q[q0+c][g*8 .. g*8+7] (+32)
  const short* qrow = Qb + base + (size_t)(q0 + c) * HD + g * 8;
  const short8 qf0 = *(const short8*)(qrow);
  const short8 qf1 = *(const short8*)(qrow + 32);

  float4v O0 = {0.f,0.f,0.f,0.f}, O1 = O0, O2 = O0, O3 = O0;
  float m = -1e30f, l = 0.0f;
  const int q = q0 + c;

  const int lo = is_global ? 0 : q0 - 128;
  const int hi = is_global ? (NS - 1) : q0 + 143;

  for (int kt = lo; kt <= hi; kt += 32) {
    if (kt + 31 < 0 || kt >= NS) continue;

    // --- QK^T: two 16-key score tiles ---
    const int k1c = min(max(kt + c, 0), NS - 1);
    const int k2c = min(max(kt + 16 + c, 0), NS - 1);
    const short* kr1 = Kb + base + (size_t)k1c * HD + g * 8;
    const short* kr2 = Kb + base + (size_t)k2c * HD + g * 8;
    const short8 kf10 = *(const short8*)kr1;
    const short8 kf11 = *(const short8*)(kr1 + 32);
    const short8 kf20 = *(const short8*)kr2;
    const short8 kf21 = *(const short8*)(kr2 + 32);
    float4v st1 = {0.f,0.f,0.f,0.f}, st2 = {0.f,0.f,0.f,0.f};
    st1 = __builtin_amdgcn_mfma_f32_16x16x32_bf16(kf10, qf0, st1, 0, 0, 0);
    st1 = __builtin_amdgcn_mfma_f32_16x16x32_bf16(kf11, qf1, st1, 0, 0, 0);
    st2 = __builtin_amdgcn_mfma_f32_16x16x32_bf16(kf20, qf0, st2, 0, 0, 0);
    st2 = __builtin_amdgcn_mfma_f32_16x16x32_bf16(kf21, qf1, st2, 0, 0, 0);

    // --- mask + scale; lane's scores: keys kt+4g+r (st1), +16 (st2) ---
    float s1[4], s2[4];
    float tmax = -1e30f;
#pragma unroll
    for (int r = 0; r < 4; ++r) {
      const int key1 = kt + 4 * g + r;
      const int key2 = key1 + 16;
      const bool v1 = (key1 >= 0) & (key1 < NS) &
                      (is_global | ((key1 - q <= WIN) & (q - key1 <= WIN)));
      const bool v2 = (key2 >= 0) & (key2 < NS) &
                      (is_global | ((key2 - q <= WIN) & (q - key2 <= WIN)));
      s1[r] = v1 ? st1[r] * 0.125f : -1e30f;
      s2[r] = v2 ? st2[r] * 0.125f : -1e30f;
      tmax = fmaxf(tmax, fmaxf(s1[r], s2[r]));
    }
    tmax = fmaxf(tmax, __shfl_xor(tmax, 16));
    tmax = fmaxf(tmax, __shfl_xor(tmax, 32));
    const float mn = fmaxf(m, tmax);
    const float alpha = __expf(m - mn);

    float p1[4], p2[4];
    float ts = 0.f;
#pragma unroll
    for (int r = 0; r < 4; ++r) {
      p1[r] = __expf(s1[r] - mn);
      p2[r] = __expf(s2[r] - mn);
      ts += p1[r] + p2[r];
    }
    ts += __shfl_xor(ts, 16);
    ts += __shfl_xor(ts, 32);
    l = l * alpha + ts;
    m = mn;
    O0 *= alpha; O1 *= alpha; O2 *= alpha; O3 *= alpha;

    // --- P^T -> PV B-frag: B[k=8g+j][n=c] = p_{key=kt+8g+j, q} ---
    const int srcA = (2 * (g & 1)) * 16 + c;
    const int srcB = srcA + 16;
    short8 pf;
#pragma unroll
    for (int r = 0; r < 4; ++r) {
      const float f1a = __shfl(p1[r], srcA);
      const float f1b = __shfl(p1[r], srcB);
      const float f2a = __shfl(p2[r], srcA);
      const float f2b = __shfl(p2[r], srcB);
      pf[r]     = f2bf((g < 2) ? f1a : f2a);
      pf[4 + r] = f2bf((g < 2) ? f1b : f2b);
    }

    // --- PV: O^T[dt] += V^T-frag x P^T-frag ---
    const int ks = min(max(kt + 8 * g, 0), NS - 8);
    const short* vrow = VT + base + (size_t)c * NS + ks;
    const short8 vf0 = *(const short8*)(vrow);
    const short8 vf1 = *(const short8*)(vrow + 16 * NS);
    const short8 vf2 = *(const short8*)(vrow + 32 * NS);
    const short8 vf3 = *(const short8*)(vrow + 48 * NS);
    O0 = __builtin_amdgcn_mfma_f32_16x16x32_bf16(vf0, pf, O0, 0, 0, 0);
    O1 = __builtin_amdgcn_mfma_f32_16x16x32_bf16(vf1, pf, O1, 0, 0, 0);
    O2 = __builtin_amdgcn_mfma_f32_16x16x32_bf16(vf2, pf, O2, 0, 0, 0);
    O3 = __builtin_amdgcn_mfma_f32_16x16x32_bf16(vf3, pf, O3, 0, 0, 0);
  }

  // --- epilogue: CTX[b][s][h][d] = O^T / l ---
  const float inv = 1.0f / l;
  float* crow = CTX + ((size_t)(b * NS + q) * NH + h) * HD;
#pragma unroll
  for (int r = 0; r < 4; ++r) {
    const int d = 4 * g + r;
    crow[d]      = O0[r] * inv;
    crow[d + 16] = O1[r] * inv;
    crow[d + 32] = O2[r] * inv;
    crow[d + 48] = O3[r] * inv;
  }
}

// ---------------------------------------------------------------------------
// Kernel 3: out = CTX @ Wout + bout  -> fp32
// ---------------------------------------------------------------------------
__global__ __launch_bounds__(256) void out_proj_kernel(
    const float* __restrict__ CTX,             // [4096][768] fp32
    const float* __restrict__ Wout,            // [768][768]
    const float* __restrict__ bout,            // [768]
    float* __restrict__ out)                   // [4096][768]
{
  __shared__ float As[16][66];
  __shared__ float Bs[16][66];
  const int bn = blockIdx.x * 64;
  const int bm = blockIdx.y * 64;
  const int tid = threadIdx.x;
  const int tm = tid >> 4;
  const int tn = tid & 15;

  float acc[4][4] = {};

  for (int k0 = 0; k0 < ND; k0 += 16) {
    for (int idx = tid; idx < 1024; idx += 256) {
      int r = idx >> 4, kk = idx & 15;
      As[kk][r] = CTX[(size_t)(bm + r) * ND + (k0 + kk)];
    }
    for (int idx = tid; idx < 1024; idx += 256) {
      int kk = idx >> 6, c = idx & 63;
      Bs[kk][c] = Wout[(size_t)(k0 + kk) * ND + (bn + c)];
    }
    __syncthreads();
#pragma unroll
    for (int kk = 0; kk < 16; ++kk) {
      float a[4], b[4];
#pragma unroll
      for (int r = 0; r < 4; ++r) a[r] = As[kk][tm * 4 + r];
#pragma unroll
      for (int c = 0; c < 4; ++c) b[c] = Bs[kk][tn * 4 + c];
#pragma unroll
      for (int r = 0; r < 4; ++r)
#pragma unroll
        for (int c = 0; c < 4; ++c) acc[r][c] += a[r] * b[c];
    }
    __syncthreads();
  }

#pragma unroll
  for (int r = 0; r < 4; ++r) {
    const int m = bm + tm * 4 + r;
#pragma unroll
    for (int c = 0; c < 4; ++c) {
      const int n = bn + tn * 4 + c;
      out[(size_t)m * ND + n] = acc[r][c] + bout[n];
    }
  }
}

// ---------------------------------------------------------------------------
extern "C" void kernel_launch(void* const* d_in, const int* in_sizes, int n_in,
                              void* d_out, int out_size, void* d_ws, size_t ws_size,
                              hipStream_t stream) {
  const float* x    = (const float*)d_in[0];
  const float* Wqkv = (const float*)d_in[1];
  const float* bqkv = (const float*)d_in[2];
  const float* Wout = (const float*)d_in[3];
  const float* bout = (const float*)d_in[4];
  const int* layer_idx = (const int*)d_in[5];

  short* Qb = (short*)d_ws;
  short* Kb = Qb + (size_t)QKN;
  short* VT = Kb + (size_t)QKN;
  float* CTX = (float*)(VT + (size_t)QKN);
  // ws: 3*QKN*2 + QKN*4 = 31.5 MB

  dim3 g1(N_QKV / 64, (NB * NS) / 64);   // (36, 64)
  qkv_rope_kernel<<<g1, 256, 0, stream>>>(x, Wqkv, bqkv, layer_idx, Qb, Kb, VT);

  const int nblk = NB * NH * (NS / 64);  // 768
  attn_mfma_kernel<<<nblk, 256, 0, stream>>>(Qb, Kb, VT, CTX, layer_idx);

  dim3 g3(ND / 64, (NB * NS) / 64);      // (12, 64)
  out_proj_kernel<<<g3, 256, 0, stream>>>(CTX, Wout, bout, (float*)d_out);
}

// Round 4
// 325.996 us; speedup vs baseline: 4.1061x; 1.5759x over previous
//
#include <hip/hip_runtime.h>
#include <hip/hip_bf16.h>
#include <math.h>

#define NB 2
#define NS 2048
#define ND 768
#define NH 12
#define HD 64
#define WIN 128
#define N_QKV 2304
#define QKN (NB * NH * NS * HD)   // 3145728

typedef __attribute__((ext_vector_type(8))) short short8;
typedef __attribute__((ext_vector_type(4))) short short4v;
typedef __attribute__((ext_vector_type(4))) float float4v;

static __device__ __forceinline__ short f2bf(float f) {
  __hip_bfloat16 h = __float2bfloat16(f);
  short s;
  __builtin_memcpy(&s, &h, 2);
  return s;
}

static __device__ __forceinline__ void async_copy16(void* lds, const void* g) {
  __builtin_amdgcn_global_load_lds(
      (const __attribute__((address_space(1))) unsigned int*)g,
      (__attribute__((address_space(3))) unsigned int*)(unsigned int)(unsigned long long)lds,
      16, 0, 0);
}

// ---------------------------------------------------------------------------
// Prep 1: fp32 -> bf16 straight copy (x). n divisible by 1024.
// ---------------------------------------------------------------------------
__global__ __launch_bounds__(256) void cvt_bf16_kernel(
    const float* __restrict__ in, short* __restrict__ out, int n)
{
  const int i = (blockIdx.x * 256 + threadIdx.x) * 4;
  if (i >= n) return;
  const float4 v = *(const float4*)(in + i);
  short4v o;
  o[0] = f2bf(v.x); o[1] = f2bf(v.y); o[2] = f2bf(v.z); o[3] = f2bf(v.w);
  *(short4v*)(out + i) = o;
}

// ---------------------------------------------------------------------------
// Prep 2: transpose fp32 [R][C] -> bf16 [C][R]. 32x32 LDS tiles, 256 thr.
// ---------------------------------------------------------------------------
__global__ __launch_bounds__(256) void transpose_bf16_kernel(
    const float* __restrict__ in, short* __restrict__ out, int R, int C)
{
  __shared__ float t[32][33];
  const int bx = blockIdx.x * 32;  // col base
  const int by = blockIdx.y * 32;  // row base
  const int tx = threadIdx.x & 31, ty = threadIdx.x >> 5;  // ty 0..7
#pragma unroll
  for (int i = 0; i < 32; i += 8)
    t[ty + i][tx] = in[(size_t)(by + ty + i) * C + bx + tx];
  __syncthreads();
#pragma unroll
  for (int i = 0; i < 32; i += 8)
    out[(size_t)(bx + ty + i) * R + by + tx] = f2bf(t[tx][ty + i]);
}

// ---------------------------------------------------------------------------
// MFMA GEMM, m97 structure: 128x128 tile, BK=32, 4 waves (each 64x64 via
// 4x4 16x16x32 bf16 frags), global_load_lds width-16 staging.
// A [M][K] bf16 row-major; Bt [N][K] bf16 row-major. Bias fp32.
// MODE 0: qkv epilogue (bias + RoPE -> Qb/Kb bf16 [bh][s][64], V -> VT
//         bf16 [bh][64][s]).  MODE 1: plain fp32 out = acc + bias.
// ---------------------------------------------------------------------------
template <int MODE>
__global__ __launch_bounds__(256) void mfma_gemm128_kernel(
    const short* __restrict__ A, const short* __restrict__ Bt,
    const float* __restrict__ bias, const int* __restrict__ layer_idx_p,
    short* __restrict__ Qb, short* __restrict__ Kb, short* __restrict__ VT,
    float* __restrict__ Out, int K, int Ncols)
{
  __shared__ short As[128 * 32];
  __shared__ short Bs[128 * 32];
  const int tid = threadIdx.x;
  const int w = tid >> 6, lane = tid & 63;
  const int c = lane & 15, g = lane >> 4;
  const int bm = blockIdx.y * 128, bn = blockIdx.x * 128;
  const int l4 = lane >> 2;            // 0..15
  const int lb = (lane & 3) * 8;       // bf16-element offset of 16B chunk

  float4v acc[4][4];
#pragma unroll
  for (int i = 0; i < 4; ++i)
#pragma unroll
    for (int j = 0; j < 4; ++j) acc[i][j] = (float4v){0.f, 0.f, 0.f, 0.f};

  const short* Ag = A + (size_t)(bm + w * 32 + l4) * K + lb;
  const short* Bg = Bt + (size_t)(bn + w * 32 + l4) * K + lb;
  short* AsW = As + w * 32 * 32;       // wave-uniform LDS stage base
  short* BsW = Bs + w * 32 * 32;

  for (int k0 = 0; k0 < K; k0 += 32) {
    async_copy16(AsW,           Ag + k0);
    async_copy16(AsW + 16 * 32, Ag + (size_t)16 * K + k0);
    async_copy16(BsW,           Bg + k0);
    async_copy16(BsW + 16 * 32, Bg + (size_t)16 * K + k0);
    __syncthreads();   // drains vmcnt -> staged data visible

    const short* aw = As + ((w >> 1) * 64 + c) * 32 + g * 8;
    const short* bw = Bs + ((w & 1) * 64 + c) * 32 + g * 8;
    short8 af[4], bf[4];
#pragma unroll
    for (int i = 0; i < 4; ++i) af[i] = *(const short8*)(aw + i * 16 * 32);
#pragma unroll
    for (int j = 0; j < 4; ++j) bf[j] = *(const short8*)(bw + j * 16 * 32);
#pragma unroll
    for (int i = 0; i < 4; ++i)
#pragma unroll
      for (int j = 0; j < 4; ++j)
        acc[i][j] = __builtin_amdgcn_mfma_f32_16x16x32_bf16(af[i], bf[j], acc[i][j], 0, 0, 0);
    __syncthreads();   // protect LDS before next stage
  }

  const int wm = bm + (w >> 1) * 64;
  const int wn = bn + (w & 1) * 64;
  float bj[4];
#pragma unroll
  for (int j = 0; j < 4; ++j) bj[j] = bias[wn + j * 16 + c];

  if (MODE == 1) {
#pragma unroll
    for (int i = 0; i < 4; ++i)
#pragma unroll
      for (int j = 0; j < 4; ++j)
#pragma unroll
        for (int r = 0; r < 4; ++r)
          Out[(size_t)(wm + i * 16 + 4 * g + r) * Ncols + wn + j * 16 + c] =
              acc[i][j][r] + bj[j];
  } else {
    const int which = bn / ND;               // uniform per block (768%128==0)
    const int hd0 = wn - which * ND;         // 64-aligned
    const int h = hd0 >> 6;
    const int bidx = bm >> 11;
    const int srow = (bm & (NS - 1)) + (w >> 1) * 64;

    if (which == 2) {
      // V: no RoPE; VT[bh][d][s], short4 along s
#pragma unroll
      for (int j = 0; j < 4; ++j) {
        const int d = j * 16 + c;
        short* vbase = VT + ((size_t)(bidx * NH + h) * HD + d) * NS;
#pragma unroll
        for (int i = 0; i < 4; ++i) {
          short4v v4;
#pragma unroll
          for (int r = 0; r < 4; ++r) v4[r] = f2bf(acc[i][j][r] + bj[j]);
          *(short4v*)(vbase + srow + i * 16 + 4 * g) = v4;
        }
      }
    } else {
      const bool is_global = ((*layer_idx_p) % 3) == 0;
      const float theta = is_global ? 160000.0f : 10000.0f;
      short* dst = which ? Kb : Qb;
      const bool oddc = (c & 1);
#pragma unroll
      for (int j = 0; j < 4; ++j) {
        const int d = j * 16 + c;
        const float freq = powf(theta, -(float)(d & ~1) / 64.0f);
#pragma unroll
        for (int i = 0; i < 4; ++i) {
#pragma unroll
          for (int r = 0; r < 4; ++r) {
            const float val = acc[i][j][r] + bj[j];
            const float partner = __shfl_xor(val, 1);
            const int s = srow + i * 16 + 4 * g + r;
            float sn, cs;
            sincosf((float)s * freq, &sn, &cs);
            const float o = oddc ? (val * cs + partner * sn)
                                 : (val * cs - partner * sn);
            dst[((size_t)(bidx * NH + h) * NS + s) * HD + d] = f2bf(o);
          }
        }
      }
    }
  }
}

// ---------------------------------------------------------------------------
// MFMA banded flash attention (unchanged from R2 except bf16 CTX store).
// ---------------------------------------------------------------------------
__global__ __launch_bounds__(256) void attn_mfma_kernel(
    const short* __restrict__ Qb, const short* __restrict__ Kb,
    const short* __restrict__ VT, short* __restrict__ CTXb,
    const int* __restrict__ layer_idx_p)
{
  const int lane = threadIdx.x & 63;
  const int wv = threadIdx.x >> 6;
  const int c = lane & 15;
  const int g = lane >> 4;
  const int bh = blockIdx.x >> 5;
  const int qt = blockIdx.x & 31;
  const int b = bh / NH;
  const int h = bh - b * NH;
  const int q0 = qt * 64 + wv * 16;
  const bool is_global = ((*layer_idx_p) % 3) == 0;
  const size_t base = (size_t)bh * NS * HD;

  const short* qrow = Qb + base + (size_t)(q0 + c) * HD + g * 8;
  const short8 qf0 = *(const short8*)(qrow);
  const short8 qf1 = *(const short8*)(qrow + 32);

  float4v O0 = {0.f, 0.f, 0.f, 0.f}, O1 = O0, O2 = O0, O3 = O0;
  float m = -1e30f, l = 0.0f;
  const int q = q0 + c;

  const int lo = is_global ? 0 : q0 - 128;
  const int hi = is_global ? (NS - 1) : q0 + 143;

  for (int kt = lo; kt <= hi; kt += 32) {
    if (kt + 31 < 0 || kt >= NS) continue;

    const int k1c = min(max(kt + c, 0), NS - 1);
    const int k2c = min(max(kt + 16 + c, 0), NS - 1);
    const short* kr1 = Kb + base + (size_t)k1c * HD + g * 8;
    const short* kr2 = Kb + base + (size_t)k2c * HD + g * 8;
    const short8 kf10 = *(const short8*)kr1;
    const short8 kf11 = *(const short8*)(kr1 + 32);
    const short8 kf20 = *(const short8*)kr2;
    const short8 kf21 = *(const short8*)(kr2 + 32);
    float4v st1 = {0.f, 0.f, 0.f, 0.f}, st2 = {0.f, 0.f, 0.f, 0.f};
    st1 = __builtin_amdgcn_mfma_f32_16x16x32_bf16(kf10, qf0, st1, 0, 0, 0);
    st1 = __builtin_amdgcn_mfma_f32_16x16x32_bf16(kf11, qf1, st1, 0, 0, 0);
    st2 = __builtin_amdgcn_mfma_f32_16x16x32_bf16(kf20, qf0, st2, 0, 0, 0);
    st2 = __builtin_amdgcn_mfma_f32_16x16x32_bf16(kf21, qf1, st2, 0, 0, 0);

    float s1[4], s2[4];
    float tmax = -1e30f;
#pragma unroll
    for (int r = 0; r < 4; ++r) {
      const int key1 = kt + 4 * g + r;
      const int key2 = key1 + 16;
      const bool v1 = (key1 >= 0) & (key1 < NS) &
                      (is_global | ((key1 - q <= WIN) & (q - key1 <= WIN)));
      const bool v2 = (key2 >= 0) & (key2 < NS) &
                      (is_global | ((key2 - q <= WIN) & (q - key2 <= WIN)));
      s1[r] = v1 ? st1[r] * 0.125f : -1e30f;
      s2[r] = v2 ? st2[r] * 0.125f : -1e30f;
      tmax = fmaxf(tmax, fmaxf(s1[r], s2[r]));
    }
    tmax = fmaxf(tmax, __shfl_xor(tmax, 16));
    tmax = fmaxf(tmax, __shfl_xor(tmax, 32));
    const float mn = fmaxf(m, tmax);
    const float alpha = __expf(m - mn);

    float p1[4], p2[4];
    float ts = 0.f;
#pragma unroll
    for (int r = 0; r < 4; ++r) {
      p1[r] = __expf(s1[r] - mn);
      p2[r] = __expf(s2[r] - mn);
      ts += p1[r] + p2[r];
    }
    ts += __shfl_xor(ts, 16);
    ts += __shfl_xor(ts, 32);
    l = l * alpha + ts;
    m = mn;
    O0 *= alpha; O1 *= alpha; O2 *= alpha; O3 *= alpha;

    const int srcA = (2 * (g & 1)) * 16 + c;
    const int srcB = srcA + 16;
    short8 pf;
#pragma unroll
    for (int r = 0; r < 4; ++r) {
      const float f1a = __shfl(p1[r], srcA);
      const float f1b = __shfl(p1[r], srcB);
      const float f2a = __shfl(p2[r], srcA);
      const float f2b = __shfl(p2[r], srcB);
      pf[r]     = f2bf((g < 2) ? f1a : f2a);
      pf[4 + r] = f2bf((g < 2) ? f1b : f2b);
    }

    const int ks = min(max(kt + 8 * g, 0), NS - 8);
    const short* vrow = VT + base + (size_t)c * NS + ks;
    const short8 vf0 = *(const short8*)(vrow);
    const short8 vf1 = *(const short8*)(vrow + 16 * NS);
    const short8 vf2 = *(const short8*)(vrow + 32 * NS);
    const short8 vf3 = *(const short8*)(vrow + 48 * NS);
    O0 = __builtin_amdgcn_mfma_f32_16x16x32_bf16(vf0, pf, O0, 0, 0, 0);
    O1 = __builtin_amdgcn_mfma_f32_16x16x32_bf16(vf1, pf, O1, 0, 0, 0);
    O2 = __builtin_amdgcn_mfma_f32_16x16x32_bf16(vf2, pf, O2, 0, 0, 0);
    O3 = __builtin_amdgcn_mfma_f32_16x16x32_bf16(vf3, pf, O3, 0, 0, 0);
  }

  const float inv = 1.0f / l;
  short* crow = CTXb + ((size_t)(b * NS + q) * NH + h) * HD;
#pragma unroll
  for (int r = 0; r < 4; ++r) {
    const int d = 4 * g + r;
    crow[d]      = f2bf(O0[r] * inv);
    crow[d + 16] = f2bf(O1[r] * inv);
    crow[d + 32] = f2bf(O2[r] * inv);
    crow[d + 48] = f2bf(O3[r] * inv);
  }
}

// ---------------------------------------------------------------------------
extern "C" void kernel_launch(void* const* d_in, const int* in_sizes, int n_in,
                              void* d_out, int out_size, void* d_ws, size_t ws_size,
                              hipStream_t stream) {
  const float* x    = (const float*)d_in[0];
  const float* Wqkv = (const float*)d_in[1];
  const float* bqkv = (const float*)d_in[2];
  const float* Wout = (const float*)d_in[3];
  const float* bout = (const float*)d_in[4];
  const int* layer_idx = (const int*)d_in[5];

  short* xb    = (short*)d_ws;                         // [4096][768]
  short* Wqkvt = xb + (size_t)NB * NS * ND;            // [2304][768]
  short* Woutt = Wqkvt + (size_t)ND * N_QKV;           // [768][768]
  short* Qb    = Woutt + (size_t)ND * ND;              // [bh][s][64]
  short* Kb    = Qb + (size_t)QKN;
  short* VT    = Kb + (size_t)QKN;                     // [bh][64][s]
  short* CTXb  = VT + (size_t)QKN;                     // [4096][768]
  // total: 18087936 shorts = 36.2 MB

  const int nX = NB * NS * ND;  // 3145728
  cvt_bf16_kernel<<<nX / 1024, 256, 0, stream>>>(x, xb, nX);
  transpose_bf16_kernel<<<dim3(N_QKV / 32, ND / 32), 256, 0, stream>>>(Wqkv, Wqkvt, ND, N_QKV);
  transpose_bf16_kernel<<<dim3(ND / 32, ND / 32), 256, 0, stream>>>(Wout, Woutt, ND, ND);

  // QKV GEMM + RoPE: M=4096, N=2304, K=768
  mfma_gemm128_kernel<0><<<dim3(N_QKV / 128, (NB * NS) / 128), 256, 0, stream>>>(
      xb, Wqkvt, bqkv, layer_idx, Qb, Kb, VT, nullptr, ND, N_QKV);

  attn_mfma_kernel<<<NB * NH * (NS / 64), 256, 0, stream>>>(Qb, Kb, VT, CTXb, layer_idx);

  // Out projection: M=4096, N=768, K=768
  mfma_gemm128_kernel<1><<<dim3(ND / 128, (NB * NS) / 128), 256, 0, stream>>>(
      CTXb, Woutt, bout, layer_idx, nullptr, nullptr, nullptr, (float*)d_out, ND, ND);
}

// Round 6
// 176.921 us; speedup vs baseline: 7.5659x; 1.8426x over previous
//
#include <hip/hip_runtime.h>
#include <hip/hip_bf16.h>
#include <math.h>

#define NB 2
#define NS 2048
#define ND 768
#define NH 12
#define HD 64
#define WIN 128
#define N_QKV 2304
#define QKN (NB * NH * NS * HD)   // 3145728

typedef __attribute__((ext_vector_type(8))) short short8;
typedef __attribute__((ext_vector_type(4))) short short4v;
typedef __attribute__((ext_vector_type(4))) float float4v;

static __device__ __forceinline__ short f2bf(float f) {
  __hip_bfloat16 h = __float2bfloat16(f);
  short s;
  __builtin_memcpy(&s, &h, 2);
  return s;
}

static __device__ __forceinline__ void async_copy16(void* lds, const void* g) {
  __builtin_amdgcn_global_load_lds(
      (const __attribute__((address_space(1))) unsigned int*)g,
      (__attribute__((address_space(3))) unsigned int*)(unsigned int)(unsigned long long)lds,
      16, 0, 0);
}

// ---------------------------------------------------------------------------
// Prep 1: fp32 -> bf16 straight copy (x). n divisible by 1024.
// ---------------------------------------------------------------------------
__global__ __launch_bounds__(256) void cvt_bf16_kernel(
    const float* __restrict__ in, short* __restrict__ out, int n)
{
  const int i = (blockIdx.x * 256 + threadIdx.x) * 4;
  if (i >= n) return;
  const float4 v = *(const float4*)(in + i);
  short4v o;
  o[0] = f2bf(v.x); o[1] = f2bf(v.y); o[2] = f2bf(v.z); o[3] = f2bf(v.w);
  *(short4v*)(out + i) = o;
}

// ---------------------------------------------------------------------------
// Prep 2: transpose fp32 [R][C] -> bf16 [C][R]. 32x32 LDS tiles, 256 thr.
// ---------------------------------------------------------------------------
__global__ __launch_bounds__(256) void transpose_bf16_kernel(
    const float* __restrict__ in, short* __restrict__ out, int R, int C)
{
  __shared__ float t[32][33];
  const int bx = blockIdx.x * 32;  // col base
  const int by = blockIdx.y * 32;  // row base
  const int tx = threadIdx.x & 31, ty = threadIdx.x >> 5;  // ty 0..7
#pragma unroll
  for (int i = 0; i < 32; i += 8)
    t[ty + i][tx] = in[(size_t)(by + ty + i) * C + bx + tx];
  __syncthreads();
#pragma unroll
  for (int i = 0; i < 32; i += 8)
    out[(size_t)(bx + ty + i) * R + by + tx] = f2bf(t[tx][ty + i]);
}

// ---------------------------------------------------------------------------
// MFMA GEMM, m97 structure: 128x128 tile, BK=32, 4 waves (each 64x64 via
// 4x4 16x16x32 bf16 frags), global_load_lds width-16 staging.
// A [M][K] bf16 row-major; Bt [N][K] bf16 row-major. Bias fp32.
// MODE 0: qkv epilogue (bias + RoPE -> Qb/Kb bf16 [bh][s][64], V -> VT
//         bf16 [bh][64][s]).  MODE 1: plain fp32 out = acc + bias.
// NOTE: epilogue uses ONLY inlined intrinsics (__expf/__logf/__sincosf) —
// the R4 profile showed libm sincosf/powf generated ~785 MB scratch traffic.
// (__exp2f does not exist as a HIP device intrinsic — R5 compile fail.)
// ---------------------------------------------------------------------------
template <int MODE>
__global__ __launch_bounds__(256) void mfma_gemm128_kernel(
    const short* __restrict__ A, const short* __restrict__ Bt,
    const float* __restrict__ bias, const int* __restrict__ layer_idx_p,
    short* __restrict__ Qb, short* __restrict__ Kb, short* __restrict__ VT,
    float* __restrict__ Out, int K, int Ncols)
{
  __shared__ short As[128 * 32];
  __shared__ short Bs[128 * 32];
  const int tid = threadIdx.x;
  const int w = tid >> 6, lane = tid & 63;
  const int c = lane & 15, g = lane >> 4;
  const int bm = blockIdx.y * 128, bn = blockIdx.x * 128;
  const int l4 = lane >> 2;            // 0..15
  const int lb = (lane & 3) * 8;       // bf16-element offset of 16B chunk

  float4v acc[4][4];
#pragma unroll
  for (int i = 0; i < 4; ++i)
#pragma unroll
    for (int j = 0; j < 4; ++j) acc[i][j] = (float4v){0.f, 0.f, 0.f, 0.f};

  const short* Ag = A + (size_t)(bm + w * 32 + l4) * K + lb;
  const short* Bg = Bt + (size_t)(bn + w * 32 + l4) * K + lb;
  short* AsW = As + w * 32 * 32;       // wave-uniform LDS stage base
  short* BsW = Bs + w * 32 * 32;

  for (int k0 = 0; k0 < K; k0 += 32) {
    async_copy16(AsW,           Ag + k0);
    async_copy16(AsW + 16 * 32, Ag + (size_t)16 * K + k0);
    async_copy16(BsW,           Bg + k0);
    async_copy16(BsW + 16 * 32, Bg + (size_t)16 * K + k0);
    __syncthreads();   // drains vmcnt -> staged data visible

    const short* aw = As + ((w >> 1) * 64 + c) * 32 + g * 8;
    const short* bw = Bs + ((w & 1) * 64 + c) * 32 + g * 8;
    short8 af[4], bf[4];
#pragma unroll
    for (int i = 0; i < 4; ++i) af[i] = *(const short8*)(aw + i * 16 * 32);
#pragma unroll
    for (int j = 0; j < 4; ++j) bf[j] = *(const short8*)(bw + j * 16 * 32);
#pragma unroll
    for (int i = 0; i < 4; ++i)
#pragma unroll
      for (int j = 0; j < 4; ++j)
        acc[i][j] = __builtin_amdgcn_mfma_f32_16x16x32_bf16(af[i], bf[j], acc[i][j], 0, 0, 0);
    __syncthreads();   // protect LDS before next stage
  }

  const int wm = bm + (w >> 1) * 64;
  const int wn = bn + (w & 1) * 64;
  float bj[4];
#pragma unroll
  for (int j = 0; j < 4; ++j) bj[j] = bias[wn + j * 16 + c];

  if (MODE == 1) {
#pragma unroll
    for (int i = 0; i < 4; ++i)
#pragma unroll
      for (int j = 0; j < 4; ++j)
#pragma unroll
        for (int r = 0; r < 4; ++r)
          Out[(size_t)(wm + i * 16 + 4 * g + r) * Ncols + wn + j * 16 + c] =
              acc[i][j][r] + bj[j];
  } else {
    const int which = bn / ND;               // uniform per block (768%128==0)
    const int hd0 = wn - which * ND;         // 64-aligned
    const int h = hd0 >> 6;
    const int bidx = bm >> 11;
    const int srow = (bm & (NS - 1)) + (w >> 1) * 64;

    if (which == 2) {
      // V: no RoPE; VT[bh][d][s], short4 along s
#pragma unroll
      for (int j = 0; j < 4; ++j) {
        const int d = j * 16 + c;
        short* vbase = VT + ((size_t)(bidx * NH + h) * HD + d) * NS;
#pragma unroll
        for (int i = 0; i < 4; ++i) {
          short4v v4;
#pragma unroll
          for (int r = 0; r < 4; ++r) v4[r] = f2bf(acc[i][j][r] + bj[j]);
          *(short4v*)(vbase + srow + i * 16 + 4 * g) = v4;
        }
      }
    } else {
      const bool is_global = ((*layer_idx_p) % 3) == 0;
      const float theta = is_global ? 160000.0f : 10000.0f;
      const float nlt = -__logf(theta) * (1.0f / 64.0f);
      short* dst = which ? Kb : Qb;
      const bool oddc = (c & 1);
#pragma unroll
      for (int j = 0; j < 4; ++j) {
        const int d = j * 16 + c;
        const float freq = __expf((float)(d & ~1) * nlt);
#pragma unroll
        for (int i = 0; i < 4; ++i) {
#pragma unroll
          for (int r = 0; r < 4; ++r) {
            const float val = acc[i][j][r] + bj[j];
            const float partner = __shfl_xor(val, 1);
            const int s = srow + i * 16 + 4 * g + r;
            float sn, cs;
            __sincosf((float)s * freq, &sn, &cs);
            const float o = oddc ? (val * cs + partner * sn)
                                 : (val * cs - partner * sn);
            dst[((size_t)(bidx * NH + h) * NS + s) * HD + d] = f2bf(o);
          }
        }
      }
    }
  }
}

// ---------------------------------------------------------------------------
// MFMA banded flash attention (unchanged).
// ---------------------------------------------------------------------------
__global__ __launch_bounds__(256) void attn_mfma_kernel(
    const short* __restrict__ Qb, const short* __restrict__ Kb,
    const short* __restrict__ VT, short* __restrict__ CTXb,
    const int* __restrict__ layer_idx_p)
{
  const int lane = threadIdx.x & 63;
  const int wv = threadIdx.x >> 6;
  const int c = lane & 15;
  const int g = lane >> 4;
  const int bh = blockIdx.x >> 5;
  const int qt = blockIdx.x & 31;
  const int b = bh / NH;
  const int h = bh - b * NH;
  const int q0 = qt * 64 + wv * 16;
  const bool is_global = ((*layer_idx_p) % 3) == 0;
  const size_t base = (size_t)bh * NS * HD;

  const short* qrow = Qb + base + (size_t)(q0 + c) * HD + g * 8;
  const short8 qf0 = *(const short8*)(qrow);
  const short8 qf1 = *(const short8*)(qrow + 32);

  float4v O0 = {0.f, 0.f, 0.f, 0.f}, O1 = O0, O2 = O0, O3 = O0;
  float m = -1e30f, l = 0.0f;
  const int q = q0 + c;

  const int lo = is_global ? 0 : q0 - 128;
  const int hi = is_global ? (NS - 1) : q0 + 143;

  for (int kt = lo; kt <= hi; kt += 32) {
    if (kt + 31 < 0 || kt >= NS) continue;

    const int k1c = min(max(kt + c, 0), NS - 1);
    const int k2c = min(max(kt + 16 + c, 0), NS - 1);
    const short* kr1 = Kb + base + (size_t)k1c * HD + g * 8;
    const short* kr2 = Kb + base + (size_t)k2c * HD + g * 8;
    const short8 kf10 = *(const short8*)kr1;
    const short8 kf11 = *(const short8*)(kr1 + 32);
    const short8 kf20 = *(const short8*)kr2;
    const short8 kf21 = *(const short8*)(kr2 + 32);
    float4v st1 = {0.f, 0.f, 0.f, 0.f}, st2 = {0.f, 0.f, 0.f, 0.f};
    st1 = __builtin_amdgcn_mfma_f32_16x16x32_bf16(kf10, qf0, st1, 0, 0, 0);
    st1 = __builtin_amdgcn_mfma_f32_16x16x32_bf16(kf11, qf1, st1, 0, 0, 0);
    st2 = __builtin_amdgcn_mfma_f32_16x16x32_bf16(kf20, qf0, st2, 0, 0, 0);
    st2 = __builtin_amdgcn_mfma_f32_16x16x32_bf16(kf21, qf1, st2, 0, 0, 0);

    float s1[4], s2[4];
    float tmax = -1e30f;
#pragma unroll
    for (int r = 0; r < 4; ++r) {
      const int key1 = kt + 4 * g + r;
      const int key2 = key1 + 16;
      const bool v1 = (key1 >= 0) & (key1 < NS) &
                      (is_global | ((key1 - q <= WIN) & (q - key1 <= WIN)));
      const bool v2 = (key2 >= 0) & (key2 < NS) &
                      (is_global | ((key2 - q <= WIN) & (q - key2 <= WIN)));
      s1[r] = v1 ? st1[r] * 0.125f : -1e30f;
      s2[r] = v2 ? st2[r] * 0.125f : -1e30f;
      tmax = fmaxf(tmax, fmaxf(s1[r], s2[r]));
    }
    tmax = fmaxf(tmax, __shfl_xor(tmax, 16));
    tmax = fmaxf(tmax, __shfl_xor(tmax, 32));
    const float mn = fmaxf(m, tmax);
    const float alpha = __expf(m - mn);

    float p1[4], p2[4];
    float ts = 0.f;
#pragma unroll
    for (int r = 0; r < 4; ++r) {
      p1[r] = __expf(s1[r] - mn);
      p2[r] = __expf(s2[r] - mn);
      ts += p1[r] + p2[r];
    }
    ts += __shfl_xor(ts, 16);
    ts += __shfl_xor(ts, 32);
    l = l * alpha + ts;
    m = mn;
    O0 *= alpha; O1 *= alpha; O2 *= alpha; O3 *= alpha;

    const int srcA = (2 * (g & 1)) * 16 + c;
    const int srcB = srcA + 16;
    short8 pf;
#pragma unroll
    for (int r = 0; r < 4; ++r) {
      const float f1a = __shfl(p1[r], srcA);
      const float f1b = __shfl(p1[r], srcB);
      const float f2a = __shfl(p2[r], srcA);
      const float f2b = __shfl(p2[r], srcB);
      pf[r]     = f2bf((g < 2) ? f1a : f2a);
      pf[4 + r] = f2bf((g < 2) ? f1b : f2b);
    }

    const int ks = min(max(kt + 8 * g, 0), NS - 8);
    const short* vrow = VT + base + (size_t)c * NS + ks;
    const short8 vf0 = *(const short8*)(vrow);
    const short8 vf1 = *(const short8*)(vrow + 16 * NS);
    const short8 vf2 = *(const short8*)(vrow + 32 * NS);
    const short8 vf3 = *(const short8*)(vrow + 48 * NS);
    O0 = __builtin_amdgcn_mfma_f32_16x16x32_bf16(vf0, pf, O0, 0, 0, 0);
    O1 = __builtin_amdgcn_mfma_f32_16x16x32_bf16(vf1, pf, O1, 0, 0, 0);
    O2 = __builtin_amdgcn_mfma_f32_16x16x32_bf16(vf2, pf, O2, 0, 0, 0);
    O3 = __builtin_amdgcn_mfma_f32_16x16x32_bf16(vf3, pf, O3, 0, 0, 0);
  }

  const float inv = 1.0f / l;
  short* crow = CTXb + ((size_t)(b * NS + q) * NH + h) * HD;
#pragma unroll
  for (int r = 0; r < 4; ++r) {
    const int d = 4 * g + r;
    crow[d]      = f2bf(O0[r] * inv);
    crow[d + 16] = f2bf(O1[r] * inv);
    crow[d + 32] = f2bf(O2[r] * inv);
    crow[d + 48] = f2bf(O3[r] * inv);
  }
}

// ---------------------------------------------------------------------------
extern "C" void kernel_launch(void* const* d_in, const int* in_sizes, int n_in,
                              void* d_out, int out_size, void* d_ws, size_t ws_size,
                              hipStream_t stream) {
  const float* x    = (const float*)d_in[0];
  const float* Wqkv = (const float*)d_in[1];
  const float* bqkv = (const float*)d_in[2];
  const float* Wout = (const float*)d_in[3];
  const float* bout = (const float*)d_in[4];
  const int* layer_idx = (const int*)d_in[5];

  short* xb    = (short*)d_ws;                         // [4096][768]
  short* Wqkvt = xb + (size_t)NB * NS * ND;            // [2304][768]
  short* Woutt = Wqkvt + (size_t)ND * N_QKV;           // [768][768]
  short* Qb    = Woutt + (size_t)ND * ND;              // [bh][s][64]
  short* Kb    = Qb + (size_t)QKN;
  short* VT    = Kb + (size_t)QKN;                     // [bh][64][s]
  short* CTXb  = VT + (size_t)QKN;                     // [4096][768]
  // total: 18087936 shorts = 36.2 MB

  const int nX = NB * NS * ND;  // 3145728
  cvt_bf16_kernel<<<nX / 1024, 256, 0, stream>>>(x, xb, nX);
  transpose_bf16_kernel<<<dim3(N_QKV / 32, ND / 32), 256, 0, stream>>>(Wqkv, Wqkvt, ND, N_QKV);
  transpose_bf16_kernel<<<dim3(ND / 32, ND / 32), 256, 0, stream>>>(Wout, Woutt, ND, ND);

  // QKV GEMM + RoPE: M=4096, N=2304, K=768
  mfma_gemm128_kernel<0><<<dim3(N_QKV / 128, (NB * NS) / 128), 256, 0, stream>>>(
      xb, Wqkvt, bqkv, layer_idx, Qb, Kb, VT, nullptr, ND, N_QKV);

  attn_mfma_kernel<<<NB * NH * (NS / 64), 256, 0, stream>>>(Qb, Kb, VT, CTXb, layer_idx);

  // Out projection: M=4096, N=768, K=768
  mfma_gemm128_kernel<1><<<dim3(ND / 128, (NB * NS) / 128), 256, 0, stream>>>(
      CTXb, Woutt, bout, layer_idx, nullptr, nullptr, nullptr, (float*)d_out, ND, ND);
}

// Round 7
// 166.256 us; speedup vs baseline: 8.0512x; 1.0641x over previous
//
#include <hip/hip_runtime.h>
#include <hip/hip_bf16.h>
#include <math.h>

#define NB 2
#define NS 2048
#define ND 768
#define NH 12
#define HD 64
#define WIN 128
#define N_QKV 2304
#define QKN (NB * NH * NS * HD)   // 3145728

typedef __attribute__((ext_vector_type(8))) short short8;
typedef __attribute__((ext_vector_type(4))) short short4v;
typedef __attribute__((ext_vector_type(4))) float float4v;

static __device__ __forceinline__ short f2bf(float f) {
  __hip_bfloat16 h = __float2bfloat16(f);
  short s;
  __builtin_memcpy(&s, &h, 2);
  return s;
}

static __device__ __forceinline__ void async_copy16(void* lds, const void* g) {
  __builtin_amdgcn_global_load_lds(
      (const __attribute__((address_space(1))) unsigned int*)g,
      (__attribute__((address_space(3))) unsigned int*)(unsigned int)(unsigned long long)lds,
      16, 0, 0);
}

// ---------------------------------------------------------------------------
// Prep 1: fp32 -> bf16 straight copy (x). n divisible by 1024.
// ---------------------------------------------------------------------------
__global__ __launch_bounds__(256) void cvt_bf16_kernel(
    const float* __restrict__ in, short* __restrict__ out, int n)
{
  const int i = (blockIdx.x * 256 + threadIdx.x) * 4;
  if (i >= n) return;
  const float4 v = *(const float4*)(in + i);
  short4v o;
  o[0] = f2bf(v.x); o[1] = f2bf(v.y); o[2] = f2bf(v.z); o[3] = f2bf(v.w);
  *(short4v*)(out + i) = o;
}

// ---------------------------------------------------------------------------
// Prep 2: transpose fp32 [R][C] -> bf16 [C][R]. 32x32 LDS tiles, 256 thr.
// ---------------------------------------------------------------------------
__global__ __launch_bounds__(256) void transpose_bf16_kernel(
    const float* __restrict__ in, short* __restrict__ out, int R, int C)
{
  __shared__ float t[32][33];
  const int bx = blockIdx.x * 32;  // col base
  const int by = blockIdx.y * 32;  // row base
  const int tx = threadIdx.x & 31, ty = threadIdx.x >> 5;  // ty 0..7
#pragma unroll
  for (int i = 0; i < 32; i += 8)
    t[ty + i][tx] = in[(size_t)(by + ty + i) * C + bx + tx];
  __syncthreads();
#pragma unroll
  for (int i = 0; i < 32; i += 8)
    out[(size_t)(bx + ty + i) * R + by + tx] = f2bf(t[tx][ty + i]);
}

// ---------------------------------------------------------------------------
// MFMA GEMM: 128x64 tile, BK=32, 4 waves (each 32x64 via 2x4 16x16x32 bf16
// frags), global_load_lds width-16 staging. R6 geometry change: was 128x128
// (576 blocks = 2.25/CU, occupancy 11%); 128x64 doubles blocks for latency
// hiding. A [M][K] bf16 row-major; Bt [N][K] bf16 row-major. Bias fp32.
// MODE 0: qkv epilogue (bias + RoPE -> Qb/Kb bf16 [bh][s][64], V -> VT
//         bf16 [bh][64][s]).  MODE 1: plain fp32 out = acc + bias.
// Epilogue uses ONLY inlined intrinsics (__expf/__logf/__sincosf) — libm
// sincosf/powf generated ~785 MB scratch traffic (R4).
// ---------------------------------------------------------------------------
template <int MODE>
__global__ __launch_bounds__(256) void mfma_gemm128_kernel(
    const short* __restrict__ A, const short* __restrict__ Bt,
    const float* __restrict__ bias, const int* __restrict__ layer_idx_p,
    short* __restrict__ Qb, short* __restrict__ Kb, short* __restrict__ VT,
    float* __restrict__ Out, int K, int Ncols)
{
  __shared__ short As[128 * 32];   // 8 KB
  __shared__ short Bs[64 * 32];    // 4 KB
  const int tid = threadIdx.x;
  const int w = tid >> 6, lane = tid & 63;
  const int c = lane & 15, g = lane >> 4;
  const int bm = blockIdx.y * 128, bn = blockIdx.x * 64;
  const int l4 = lane >> 2;            // 0..15
  const int lb = (lane & 3) * 8;       // bf16-element offset of 16B chunk

  float4v acc[2][4];
#pragma unroll
  for (int i = 0; i < 2; ++i)
#pragma unroll
    for (int j = 0; j < 4; ++j) acc[i][j] = (float4v){0.f, 0.f, 0.f, 0.f};

  const short* Ag = A + (size_t)(bm + w * 32 + l4) * K + lb;
  const short* Bg = Bt + (size_t)(bn + w * 16 + l4) * K + lb;
  short* AsW = As + w * 32 * 32;       // wave-uniform LDS stage base
  short* BsW = Bs + w * 16 * 32;

  for (int k0 = 0; k0 < K; k0 += 32) {
    async_copy16(AsW,           Ag + k0);
    async_copy16(AsW + 16 * 32, Ag + (size_t)16 * K + k0);
    async_copy16(BsW,           Bg + k0);
    __syncthreads();   // drains vmcnt -> staged data visible

    const short* aw = As + (w * 32 + c) * 32 + g * 8;
    const short* bw = Bs + c * 32 + g * 8;
    short8 af[2], bf[4];
#pragma unroll
    for (int i = 0; i < 2; ++i) af[i] = *(const short8*)(aw + i * 16 * 32);
#pragma unroll
    for (int j = 0; j < 4; ++j) bf[j] = *(const short8*)(bw + j * 16 * 32);
#pragma unroll
    for (int i = 0; i < 2; ++i)
#pragma unroll
      for (int j = 0; j < 4; ++j)
        acc[i][j] = __builtin_amdgcn_mfma_f32_16x16x32_bf16(af[i], bf[j], acc[i][j], 0, 0, 0);
    __syncthreads();   // protect LDS before next stage
  }

  const int wm = bm + w * 32;
  const int wn = bn;
  float bj[4];
#pragma unroll
  for (int j = 0; j < 4; ++j) bj[j] = bias[wn + j * 16 + c];

  if (MODE == 1) {
#pragma unroll
    for (int i = 0; i < 2; ++i)
#pragma unroll
      for (int j = 0; j < 4; ++j)
#pragma unroll
        for (int r = 0; r < 4; ++r)
          Out[(size_t)(wm + i * 16 + 4 * g + r) * Ncols + wn + j * 16 + c] =
              acc[i][j][r] + bj[j];
  } else {
    const int which = bn / ND;               // uniform per block (768%64==0)
    const int hd0 = wn - which * ND;         // 64-aligned
    const int h = hd0 >> 6;
    const int bidx = bm >> 11;
    const int srow = (bm & (NS - 1)) + w * 32;

    if (which == 2) {
      // V: no RoPE; VT[bh][d][s], short4 along s
#pragma unroll
      for (int j = 0; j < 4; ++j) {
        const int d = j * 16 + c;
        short* vbase = VT + ((size_t)(bidx * NH + h) * HD + d) * NS;
#pragma unroll
        for (int i = 0; i < 2; ++i) {
          short4v v4;
#pragma unroll
          for (int r = 0; r < 4; ++r) v4[r] = f2bf(acc[i][j][r] + bj[j]);
          *(short4v*)(vbase + srow + i * 16 + 4 * g) = v4;
        }
      }
    } else {
      const bool is_global = ((*layer_idx_p) % 3) == 0;
      const float theta = is_global ? 160000.0f : 10000.0f;
      const float nlt = -__logf(theta) * (1.0f / 64.0f);
      short* dst = which ? Kb : Qb;
      const bool oddc = (c & 1);
#pragma unroll
      for (int j = 0; j < 4; ++j) {
        const int d = j * 16 + c;
        const float freq = __expf((float)(d & ~1) * nlt);
#pragma unroll
        for (int i = 0; i < 2; ++i) {
#pragma unroll
          for (int r = 0; r < 4; ++r) {
            const float val = acc[i][j][r] + bj[j];
            const float partner = __shfl_xor(val, 1);
            const int s = srow + i * 16 + 4 * g + r;
            float sn, cs;
            __sincosf((float)s * freq, &sn, &cs);
            const float o = oddc ? (val * cs + partner * sn)
                                 : (val * cs - partner * sn);
            dst[((size_t)(bidx * NH + h) * NS + s) * HD + d] = f2bf(o);
          }
        }
      }
    }
  }
}

// ---------------------------------------------------------------------------
// MFMA banded flash attention (unchanged).
// ---------------------------------------------------------------------------
__global__ __launch_bounds__(256) void attn_mfma_kernel(
    const short* __restrict__ Qb, const short* __restrict__ Kb,
    const short* __restrict__ VT, short* __restrict__ CTXb,
    const int* __restrict__ layer_idx_p)
{
  const int lane = threadIdx.x & 63;
  const int wv = threadIdx.x >> 6;
  const int c = lane & 15;
  const int g = lane >> 4;
  const int bh = blockIdx.x >> 5;
  const int qt = blockIdx.x & 31;
  const int b = bh / NH;
  const int h = bh - b * NH;
  const int q0 = qt * 64 + wv * 16;
  const bool is_global = ((*layer_idx_p) % 3) == 0;
  const size_t base = (size_t)bh * NS * HD;

  const short* qrow = Qb + base + (size_t)(q0 + c) * HD + g * 8;
  const short8 qf0 = *(const short8*)(qrow);
  const short8 qf1 = *(const short8*)(qrow + 32);

  float4v O0 = {0.f, 0.f, 0.f, 0.f}, O1 = O0, O2 = O0, O3 = O0;
  float m = -1e30f, l = 0.0f;
  const int q = q0 + c;

  const int lo = is_global ? 0 : q0 - 128;
  const int hi = is_global ? (NS - 1) : q0 + 143;

  for (int kt = lo; kt <= hi; kt += 32) {
    if (kt + 31 < 0 || kt >= NS) continue;

    const int k1c = min(max(kt + c, 0), NS - 1);
    const int k2c = min(max(kt + 16 + c, 0), NS - 1);
    const short* kr1 = Kb + base + (size_t)k1c * HD + g * 8;
    const short* kr2 = Kb + base + (size_t)k2c * HD + g * 8;
    const short8 kf10 = *(const short8*)kr1;
    const short8 kf11 = *(const short8*)(kr1 + 32);
    const short8 kf20 = *(const short8*)kr2;
    const short8 kf21 = *(const short8*)(kr2 + 32);
    float4v st1 = {0.f, 0.f, 0.f, 0.f}, st2 = {0.f, 0.f, 0.f, 0.f};
    st1 = __builtin_amdgcn_mfma_f32_16x16x32_bf16(kf10, qf0, st1, 0, 0, 0);
    st1 = __builtin_amdgcn_mfma_f32_16x16x32_bf16(kf11, qf1, st1, 0, 0, 0);
    st2 = __builtin_amdgcn_mfma_f32_16x16x32_bf16(kf20, qf0, st2, 0, 0, 0);
    st2 = __builtin_amdgcn_mfma_f32_16x16x32_bf16(kf21, qf1, st2, 0, 0, 0);

    float s1[4], s2[4];
    float tmax = -1e30f;
#pragma unroll
    for (int r = 0; r < 4; ++r) {
      const int key1 = kt + 4 * g + r;
      const int key2 = key1 + 16;
      const bool v1 = (key1 >= 0) & (key1 < NS) &
                      (is_global | ((key1 - q <= WIN) & (q - key1 <= WIN)));
      const bool v2 = (key2 >= 0) & (key2 < NS) &
                      (is_global | ((key2 - q <= WIN) & (q - key2 <= WIN)));
      s1[r] = v1 ? st1[r] * 0.125f : -1e30f;
      s2[r] = v2 ? st2[r] * 0.125f : -1e30f;
      tmax = fmaxf(tmax, fmaxf(s1[r], s2[r]));
    }
    tmax = fmaxf(tmax, __shfl_xor(tmax, 16));
    tmax = fmaxf(tmax, __shfl_xor(tmax, 32));
    const float mn = fmaxf(m, tmax);
    const float alpha = __expf(m - mn);

    float p1[4], p2[4];
    float ts = 0.f;
#pragma unroll
    for (int r = 0; r < 4; ++r) {
      p1[r] = __expf(s1[r] - mn);
      p2[r] = __expf(s2[r] - mn);
      ts += p1[r] + p2[r];
    }
    ts += __shfl_xor(ts, 16);
    ts += __shfl_xor(ts, 32);
    l = l * alpha + ts;
    m = mn;
    O0 *= alpha; O1 *= alpha; O2 *= alpha; O3 *= alpha;

    const int srcA = (2 * (g & 1)) * 16 + c;
    const int srcB = srcA + 16;
    short8 pf;
#pragma unroll
    for (int r = 0; r < 4; ++r) {
      const float f1a = __shfl(p1[r], srcA);
      const float f1b = __shfl(p1[r], srcB);
      const float f2a = __shfl(p2[r], srcA);
      const float f2b = __shfl(p2[r], srcB);
      pf[r]     = f2bf((g < 2) ? f1a : f2a);
      pf[4 + r] = f2bf((g < 2) ? f1b : f2b);
    }

    const int ks = min(max(kt + 8 * g, 0), NS - 8);
    const short* vrow = VT + base + (size_t)c * NS + ks;
    const short8 vf0 = *(const short8*)(vrow);
    const short8 vf1 = *(const short8*)(vrow + 16 * NS);
    const short8 vf2 = *(const short8*)(vrow + 32 * NS);
    const short8 vf3 = *(const short8*)(vrow + 48 * NS);
    O0 = __builtin_amdgcn_mfma_f32_16x16x32_bf16(vf0, pf, O0, 0, 0, 0);
    O1 = __builtin_amdgcn_mfma_f32_16x16x32_bf16(vf1, pf, O1, 0, 0, 0);
    O2 = __builtin_amdgcn_mfma_f32_16x16x32_bf16(vf2, pf, O2, 0, 0, 0);
    O3 = __builtin_amdgcn_mfma_f32_16x16x32_bf16(vf3, pf, O3, 0, 0, 0);
  }

  const float inv = 1.0f / l;
  short* crow = CTXb + ((size_t)(b * NS + q) * NH + h) * HD;
#pragma unroll
  for (int r = 0; r < 4; ++r) {
    const int d = 4 * g + r;
    crow[d]      = f2bf(O0[r] * inv);
    crow[d + 16] = f2bf(O1[r] * inv);
    crow[d + 32] = f2bf(O2[r] * inv);
    crow[d + 48] = f2bf(O3[r] * inv);
  }
}

// ---------------------------------------------------------------------------
extern "C" void kernel_launch(void* const* d_in, const int* in_sizes, int n_in,
                              void* d_out, int out_size, void* d_ws, size_t ws_size,
                              hipStream_t stream) {
  const float* x    = (const float*)d_in[0];
  const float* Wqkv = (const float*)d_in[1];
  const float* bqkv = (const float*)d_in[2];
  const float* Wout = (const float*)d_in[3];
  const float* bout = (const float*)d_in[4];
  const int* layer_idx = (const int*)d_in[5];

  short* xb    = (short*)d_ws;                         // [4096][768]
  short* Wqkvt = xb + (size_t)NB * NS * ND;            // [2304][768]
  short* Woutt = Wqkvt + (size_t)ND * N_QKV;           // [768][768]
  short* Qb    = Woutt + (size_t)ND * ND;              // [bh][s][64]
  short* Kb    = Qb + (size_t)QKN;
  short* VT    = Kb + (size_t)QKN;                     // [bh][64][s]
  short* CTXb  = VT + (size_t)QKN;                     // [4096][768]
  // total: 18087936 shorts = 36.2 MB

  const int nX = NB * NS * ND;  // 3145728
  cvt_bf16_kernel<<<nX / 1024, 256, 0, stream>>>(x, xb, nX);
  transpose_bf16_kernel<<<dim3(N_QKV / 32, ND / 32), 256, 0, stream>>>(Wqkv, Wqkvt, ND, N_QKV);
  transpose_bf16_kernel<<<dim3(ND / 32, ND / 32), 256, 0, stream>>>(Wout, Woutt, ND, ND);

  // QKV GEMM + RoPE: M=4096, N=2304, K=768
  mfma_gemm128_kernel<0><<<dim3(N_QKV / 64, (NB * NS) / 128), 256, 0, stream>>>(
      xb, Wqkvt, bqkv, layer_idx, Qb, Kb, VT, nullptr, ND, N_QKV);

  attn_mfma_kernel<<<NB * NH * (NS / 64), 256, 0, stream>>>(Qb, Kb, VT, CTXb, layer_idx);

  // Out projection: M=4096, N=768, K=768
  mfma_gemm128_kernel<1><<<dim3(ND / 64, (NB * NS) / 128), 256, 0, stream>>>(
      CTXb, Woutt, bout, layer_idx, nullptr, nullptr, nullptr, (float*)d_out, ND, ND);
}

// Round 8
// 154.789 us; speedup vs baseline: 8.6476x; 1.0741x over previous
//
#include <hip/hip_runtime.h>
#include <hip/hip_bf16.h>
#include <math.h>

#define NB 2
#define NS 2048
#define ND 768
#define NH 12
#define HD 64
#define WIN 128
#define N_QKV 2304
#define QKN (NB * NH * NS * HD)   // 3145728

typedef __attribute__((ext_vector_type(8))) short short8;
typedef __attribute__((ext_vector_type(4))) short short4v;
typedef __attribute__((ext_vector_type(4))) float float4v;

static __device__ __forceinline__ short f2bf(float f) {
  __hip_bfloat16 h = __float2bfloat16(f);
  short s;
  __builtin_memcpy(&s, &h, 2);
  return s;
}

static __device__ __forceinline__ void async_copy16(void* lds, const void* g) {
  __builtin_amdgcn_global_load_lds(
      (const __attribute__((address_space(1))) unsigned int*)g,
      (__attribute__((address_space(3))) unsigned int*)(unsigned int)(unsigned long long)lds,
      16, 0, 0);
}

// ---------------------------------------------------------------------------
// Prep 1: fp32 -> bf16 straight copy (x). n divisible by 1024.
// ---------------------------------------------------------------------------
__global__ __launch_bounds__(256) void cvt_bf16_kernel(
    const float* __restrict__ in, short* __restrict__ out, int n)
{
  const int i = (blockIdx.x * 256 + threadIdx.x) * 4;
  if (i >= n) return;
  const float4 v = *(const float4*)(in + i);
  short4v o;
  o[0] = f2bf(v.x); o[1] = f2bf(v.y); o[2] = f2bf(v.z); o[3] = f2bf(v.w);
  *(short4v*)(out + i) = o;
}

// ---------------------------------------------------------------------------
// Prep 2: transpose fp32 [R][C] -> bf16 [C][R]. 32x32 LDS tiles, 256 thr.
// ---------------------------------------------------------------------------
__global__ __launch_bounds__(256) void transpose_bf16_kernel(
    const float* __restrict__ in, short* __restrict__ out, int R, int C)
{
  __shared__ float t[32][33];
  const int bx = blockIdx.x * 32;  // col base
  const int by = blockIdx.y * 32;  // row base
  const int tx = threadIdx.x & 31, ty = threadIdx.x >> 5;  // ty 0..7
#pragma unroll
  for (int i = 0; i < 32; i += 8)
    t[ty + i][tx] = in[(size_t)(by + ty + i) * C + bx + tx];
  __syncthreads();
#pragma unroll
  for (int i = 0; i < 32; i += 8)
    out[(size_t)(bx + ty + i) * R + by + tx] = f2bf(t[tx][ty + i]);
}

// ---------------------------------------------------------------------------
// MFMA GEMM: 128x64 tile, BK=64 (R7: was BK=32 — halves barrier count),
// 4 waves each 32x64 via 2x4 16x16x32 bf16 frags, global_load_lds width-16.
// LDS K-chunk slots are XOR-swizzled by row&7 (slot = chunk ^ (row&7)):
// kills the 8-way ds_read_b128 bank conflict (R6: 1.77e6 conflict cycles).
// Legal because global_load_lds takes a PER-LANE global address; only the
// LDS dest is forced to base+lane*16.
// A [M][K] bf16 row-major; Bt [N][K] bf16 row-major. Bias fp32.
// MODE 0: qkv epilogue (bias + RoPE -> Qb/Kb bf16 [bh][s][64], V -> VT
//         bf16 [bh][64][s]).  MODE 1: plain fp32 out = acc + bias.
// Epilogue uses ONLY inlined intrinsics — libm sincosf/powf generated
// ~785 MB scratch traffic (R4).
// ---------------------------------------------------------------------------
template <int MODE>
__global__ __launch_bounds__(256) void mfma_gemm128_kernel(
    const short* __restrict__ A, const short* __restrict__ Bt,
    const float* __restrict__ bias, const int* __restrict__ layer_idx_p,
    short* __restrict__ Qb, short* __restrict__ Kb, short* __restrict__ VT,
    float* __restrict__ Out, int K, int Ncols)
{
  __shared__ short As[128 * 64];   // 16 KB
  __shared__ short Bs[64 * 64];    //  8 KB
  const int tid = threadIdx.x;
  const int w = tid >> 6, lane = tid & 63;
  const int c = lane & 15, g = lane >> 4;
  const int bm = blockIdx.y * 128, bn = blockIdx.x * 64;
  const int lr = lane >> 3;            // staging row 0..7
  const int gch = (lane & 7) ^ lr;     // swizzled global K-chunk index

  float4v acc[2][4];
#pragma unroll
  for (int i = 0; i < 2; ++i)
#pragma unroll
    for (int j = 0; j < 4; ++j) acc[i][j] = (float4v){0.f, 0.f, 0.f, 0.f};

  const short* Ag = A + (size_t)(bm + w * 32 + lr) * K + gch * 8;
  const short* Bg = Bt + (size_t)(bn + w * 16 + lr) * K + gch * 8;
  short* AsW = As + (w * 32) * 64;     // wave-uniform LDS stage base
  short* BsW = Bs + (w * 16) * 64;

  const int cl7 = c & 7;
  const short* aw = As + (w * 32 + c) * 64;
  const short* bwp = Bs + c * 64;

  for (int k0 = 0; k0 < K; k0 += 64) {
    async_copy16(AsW,            Ag + k0);
    async_copy16(AsW + 512,      Ag + k0 + (size_t)8 * K);
    async_copy16(AsW + 1024,     Ag + k0 + (size_t)16 * K);
    async_copy16(AsW + 1536,     Ag + k0 + (size_t)24 * K);
    async_copy16(BsW,            Bg + k0);
    async_copy16(BsW + 512,      Bg + k0 + (size_t)8 * K);
    __syncthreads();   // drains vmcnt -> staged data visible

    short8 af[2][2], bfr[4][2];
#pragma unroll
    for (int t = 0; t < 2; ++t) {
      const int slot = ((t * 4 + g) ^ cl7) * 8;
#pragma unroll
      for (int i = 0; i < 2; ++i) af[i][t] = *(const short8*)(aw + i * 16 * 64 + slot);
#pragma unroll
      for (int j = 0; j < 4; ++j) bfr[j][t] = *(const short8*)(bwp + j * 16 * 64 + slot);
    }
#pragma unroll
    for (int t = 0; t < 2; ++t)
#pragma unroll
      for (int i = 0; i < 2; ++i)
#pragma unroll
        for (int j = 0; j < 4; ++j)
          acc[i][j] = __builtin_amdgcn_mfma_f32_16x16x32_bf16(af[i][t], bfr[j][t], acc[i][j], 0, 0, 0);
    __syncthreads();   // protect LDS before next stage
  }

  const int wm = bm + w * 32;
  const int wn = bn;
  float bj[4];
#pragma unroll
  for (int j = 0; j < 4; ++j) bj[j] = bias[wn + j * 16 + c];

  if (MODE == 1) {
#pragma unroll
    for (int i = 0; i < 2; ++i)
#pragma unroll
      for (int j = 0; j < 4; ++j)
#pragma unroll
        for (int r = 0; r < 4; ++r)
          Out[(size_t)(wm + i * 16 + 4 * g + r) * Ncols + wn + j * 16 + c] =
              acc[i][j][r] + bj[j];
  } else {
    const int which = bn / ND;               // uniform per block (768%64==0)
    const int hd0 = wn - which * ND;         // 64-aligned
    const int h = hd0 >> 6;
    const int bidx = bm >> 11;
    const int srow = (bm & (NS - 1)) + w * 32;

    if (which == 2) {
      // V: no RoPE; VT[bh][d][s], short4 along s
#pragma unroll
      for (int j = 0; j < 4; ++j) {
        const int d = j * 16 + c;
        short* vbase = VT + ((size_t)(bidx * NH + h) * HD + d) * NS;
#pragma unroll
        for (int i = 0; i < 2; ++i) {
          short4v v4;
#pragma unroll
          for (int r = 0; r < 4; ++r) v4[r] = f2bf(acc[i][j][r] + bj[j]);
          *(short4v*)(vbase + srow + i * 16 + 4 * g) = v4;
        }
      }
    } else {
      const bool is_global = ((*layer_idx_p) % 3) == 0;
      const float theta = is_global ? 160000.0f : 10000.0f;
      const float nlt = -__logf(theta) * (1.0f / 64.0f);
      short* dst = which ? Kb : Qb;
      const bool oddc = (c & 1);
#pragma unroll
      for (int j = 0; j < 4; ++j) {
        const int d = j * 16 + c;
        const float freq = __expf((float)(d & ~1) * nlt);
#pragma unroll
        for (int i = 0; i < 2; ++i) {
#pragma unroll
          for (int r = 0; r < 4; ++r) {
            const float val = acc[i][j][r] + bj[j];
            const float partner = __shfl_xor(val, 1);
            const int s = srow + i * 16 + 4 * g + r;
            float sn, cs;
            __sincosf((float)s * freq, &sn, &cs);
            const float o = oddc ? (val * cs + partner * sn)
                                 : (val * cs - partner * sn);
            dst[((size_t)(bidx * NH + h) * NS + s) * HD + d] = f2bf(o);
          }
        }
      }
    }
  }
}

// ---------------------------------------------------------------------------
// MFMA banded flash attention. R7 change: NO online softmax — scores are
// provably bounded (|q·k|/8 <~ 15, exp never overflows fp32), so we use a
// fixed reference: p = exp(s*scale), masked -> exp(-1e30) = 0. Removes the
// per-iteration cross-lane reductions and O-rescale from the carried chain;
// iterations now pipeline (O/l are associative accumulates). l is reduced
// across quads ONCE in the epilogue.
// ---------------------------------------------------------------------------
__global__ __launch_bounds__(256) void attn_mfma_kernel(
    const short* __restrict__ Qb, const short* __restrict__ Kb,
    const short* __restrict__ VT, short* __restrict__ CTXb,
    const int* __restrict__ layer_idx_p)
{
  const int lane = threadIdx.x & 63;
  const int wv = threadIdx.x >> 6;
  const int c = lane & 15;
  const int g = lane >> 4;
  const int bh = blockIdx.x >> 5;
  const int qt = blockIdx.x & 31;
  const int b = bh / NH;
  const int h = bh - b * NH;
  const int q0 = qt * 64 + wv * 16;
  const bool is_global = ((*layer_idx_p) % 3) == 0;
  const size_t base = (size_t)bh * NS * HD;

  const short* qrow = Qb + base + (size_t)(q0 + c) * HD + g * 8;
  const short8 qf0 = *(const short8*)(qrow);
  const short8 qf1 = *(const short8*)(qrow + 32);

  float4v O0 = {0.f, 0.f, 0.f, 0.f}, O1 = O0, O2 = O0, O3 = O0;
  float lacc = 0.0f;
  const int q = q0 + c;

  const int lo = is_global ? 0 : q0 - 128;
  const int hi = is_global ? (NS - 1) : q0 + 143;

  for (int kt = lo; kt <= hi; kt += 32) {
    if (kt + 31 < 0 || kt >= NS) continue;

    const int k1c = min(max(kt + c, 0), NS - 1);
    const int k2c = min(max(kt + 16 + c, 0), NS - 1);
    const short* kr1 = Kb + base + (size_t)k1c * HD + g * 8;
    const short* kr2 = Kb + base + (size_t)k2c * HD + g * 8;
    const short8 kf10 = *(const short8*)kr1;
    const short8 kf11 = *(const short8*)(kr1 + 32);
    const short8 kf20 = *(const short8*)kr2;
    const short8 kf21 = *(const short8*)(kr2 + 32);
    float4v st1 = {0.f, 0.f, 0.f, 0.f}, st2 = {0.f, 0.f, 0.f, 0.f};
    st1 = __builtin_amdgcn_mfma_f32_16x16x32_bf16(kf10, qf0, st1, 0, 0, 0);
    st1 = __builtin_amdgcn_mfma_f32_16x16x32_bf16(kf11, qf1, st1, 0, 0, 0);
    st2 = __builtin_amdgcn_mfma_f32_16x16x32_bf16(kf20, qf0, st2, 0, 0, 0);
    st2 = __builtin_amdgcn_mfma_f32_16x16x32_bf16(kf21, qf1, st2, 0, 0, 0);

    float p1[4], p2[4];
#pragma unroll
    for (int r = 0; r < 4; ++r) {
      const int key1 = kt + 4 * g + r;
      const int key2 = key1 + 16;
      const bool v1 = (key1 >= 0) & (key1 < NS) &
                      (is_global | ((key1 - q <= WIN) & (q - key1 <= WIN)));
      const bool v2 = (key2 >= 0) & (key2 < NS) &
                      (is_global | ((key2 - q <= WIN) & (q - key2 <= WIN)));
      p1[r] = __expf(v1 ? st1[r] * 0.125f : -1e30f);
      p2[r] = __expf(v2 ? st2[r] * 0.125f : -1e30f);
      lacc += p1[r] + p2[r];
    }

    const int srcA = (2 * (g & 1)) * 16 + c;
    const int srcB = srcA + 16;
    short8 pf;
#pragma unroll
    for (int r = 0; r < 4; ++r) {
      const float f1a = __shfl(p1[r], srcA);
      const float f1b = __shfl(p1[r], srcB);
      const float f2a = __shfl(p2[r], srcA);
      const float f2b = __shfl(p2[r], srcB);
      pf[r]     = f2bf((g < 2) ? f1a : f2a);
      pf[4 + r] = f2bf((g < 2) ? f1b : f2b);
    }

    const int ks = min(max(kt + 8 * g, 0), NS - 8);
    const short* vrow = VT + base + (size_t)c * NS + ks;
    const short8 vf0 = *(const short8*)(vrow);
    const short8 vf1 = *(const short8*)(vrow + 16 * NS);
    const short8 vf2 = *(const short8*)(vrow + 32 * NS);
    const short8 vf3 = *(const short8*)(vrow + 48 * NS);
    O0 = __builtin_amdgcn_mfma_f32_16x16x32_bf16(vf0, pf, O0, 0, 0, 0);
    O1 = __builtin_amdgcn_mfma_f32_16x16x32_bf16(vf1, pf, O1, 0, 0, 0);
    O2 = __builtin_amdgcn_mfma_f32_16x16x32_bf16(vf2, pf, O2, 0, 0, 0);
    O3 = __builtin_amdgcn_mfma_f32_16x16x32_bf16(vf3, pf, O3, 0, 0, 0);
  }

  // epilogue: one cross-quad reduction of l, then scale+store
  lacc += __shfl_xor(lacc, 16);
  lacc += __shfl_xor(lacc, 32);
  const float inv = 1.0f / lacc;
  short* crow = CTXb + ((size_t)(b * NS + q) * NH + h) * HD;
#pragma unroll
  for (int r = 0; r < 4; ++r) {
    const int d = 4 * g + r;
    crow[d]      = f2bf(O0[r] * inv);
    crow[d + 16] = f2bf(O1[r] * inv);
    crow[d + 32] = f2bf(O2[r] * inv);
    crow[d + 48] = f2bf(O3[r] * inv);
  }
}

// ---------------------------------------------------------------------------
extern "C" void kernel_launch(void* const* d_in, const int* in_sizes, int n_in,
                              void* d_out, int out_size, void* d_ws, size_t ws_size,
                              hipStream_t stream) {
  const float* x    = (const float*)d_in[0];
  const float* Wqkv = (const float*)d_in[1];
  const float* bqkv = (const float*)d_in[2];
  const float* Wout = (const float*)d_in[3];
  const float* bout = (const float*)d_in[4];
  const int* layer_idx = (const int*)d_in[5];

  short* xb    = (short*)d_ws;                         // [4096][768]
  short* Wqkvt = xb + (size_t)NB * NS * ND;            // [2304][768]
  short* Woutt = Wqkvt + (size_t)ND * N_QKV;           // [768][768]
  short* Qb    = Woutt + (size_t)ND * ND;              // [bh][s][64]
  short* Kb    = Qb + (size_t)QKN;
  short* VT    = Kb + (size_t)QKN;                     // [bh][64][s]
  short* CTXb  = VT + (size_t)QKN;                     // [4096][768]
  // total: 18087936 shorts = 36.2 MB

  const int nX = NB * NS * ND;  // 3145728
  cvt_bf16_kernel<<<nX / 1024, 256, 0, stream>>>(x, xb, nX);
  transpose_bf16_kernel<<<dim3(N_QKV / 32, ND / 32), 256, 0, stream>>>(Wqkv, Wqkvt, ND, N_QKV);
  transpose_bf16_kernel<<<dim3(ND / 32, ND / 32), 256, 0, stream>>>(Wout, Woutt, ND, ND);

  // QKV GEMM + RoPE: M=4096, N=2304, K=768
  mfma_gemm128_kernel<0><<<dim3(N_QKV / 64, (NB * NS) / 128), 256, 0, stream>>>(
      xb, Wqkvt, bqkv, layer_idx, Qb, Kb, VT, nullptr, ND, N_QKV);

  attn_mfma_kernel<<<NB * NH * (NS / 64), 256, 0, stream>>>(Qb, Kb, VT, CTXb, layer_idx);

  // Out projection: M=4096, N=768, K=768
  mfma_gemm128_kernel<1><<<dim3(ND / 64, (NB * NS) / 128), 256, 0, stream>>>(
      CTXb, Woutt, bout, layer_idx, nullptr, nullptr, nullptr, (float*)d_out, ND, ND);
}

// Round 10
// 150.957 us; speedup vs baseline: 8.8671x; 1.0254x over previous
//
#include <hip/hip_runtime.h>
#include <hip/hip_bf16.h>
#include <math.h>

#define NB 2
#define NS 2048
#define ND 768
#define NH 12
#define HD 64
#define WIN 128
#define N_QKV 2304
#define QKN (NB * NH * NS * HD)   // 3145728

typedef __attribute__((ext_vector_type(8))) short short8;
typedef __attribute__((ext_vector_type(4))) short short4v;
typedef __attribute__((ext_vector_type(4))) float float4v;

static __device__ __forceinline__ short f2bf(float f) {
  __hip_bfloat16 h = __float2bfloat16(f);
  short s;
  __builtin_memcpy(&s, &h, 2);
  return s;
}

static __device__ __forceinline__ void async_copy16(void* lds, const void* g) {
  __builtin_amdgcn_global_load_lds(
      (const __attribute__((address_space(1))) unsigned int*)g,
      (__attribute__((address_space(3))) unsigned int*)(unsigned int)(unsigned long long)lds,
      16, 0, 0);
}

// ---------------------------------------------------------------------------
// Merged prep kernel (R9: was 3 dispatches — cvt + 2 transposes).
// unit u: [0,3072)      x fp32 -> bf16, 1024 elts/unit
//         [3072,4800)   Wqkv [768][2304] -> Wqkvt [2304][768] bf16, 32x32 tile
//         [4800,5376)   Wout [768][768]  -> Woutt [768][768]  bf16, 32x32 tile
// ---------------------------------------------------------------------------
__global__ __launch_bounds__(256) void prep_kernel(
    const float* __restrict__ x, const float* __restrict__ Wqkv,
    const float* __restrict__ Wout, short* __restrict__ xb,
    short* __restrict__ Wqkvt, short* __restrict__ Woutt)
{
  __shared__ float t[32][33];
  const int u = blockIdx.x;
  const int tid = threadIdx.x;

  if (u < 3072) {
    const int i = u * 1024 + tid * 4;
    const float4 v = *(const float4*)(x + i);
    short4v o;
    o[0] = f2bf(v.x); o[1] = f2bf(v.y); o[2] = f2bf(v.z); o[3] = f2bf(v.w);
    *(short4v*)(xb + i) = o;
    return;
  }

  const bool isqkv = (u < 4800);
  const float* in = isqkv ? Wqkv : Wout;
  short* out = isqkv ? Wqkvt : Woutt;
  const int C = isqkv ? N_QKV : ND;       // in cols
  const int tt = u - (isqkv ? 3072 : 4800);
  const int nbx = C / 32;
  const int bx = (tt % nbx) * 32;         // col base
  const int by = (tt / nbx) * 32;         // row base
  const int tx = tid & 31, ty = tid >> 5; // ty 0..7
#pragma unroll
  for (int i = 0; i < 32; i += 8)
    t[ty + i][tx] = in[(size_t)(by + ty + i) * C + bx + tx];
  __syncthreads();
#pragma unroll
  for (int i = 0; i < 32; i += 8)
    out[(size_t)(bx + ty + i) * ND + by + tx] = f2bf(t[tx][ty + i]);
}

// ---------------------------------------------------------------------------
// MFMA GEMM: 128x64 tile, BK=64, 4 waves each 32x64 via 2x4 16x16x32 bf16
// frags, global_load_lds width-16 staging, XOR-swizzled K-chunk slots
// (kills the 8-way ds_read_b128 bank conflict; legal because
// global_load_lds takes a per-lane GLOBAL address, only the LDS dest is
// forced to base+lane*16).
// A [M][K] bf16 row-major; Bt [N][K] bf16 row-major. Bias fp32.
// MODE 0: qkv epilogue (bias + RoPE -> Qb/Kb bf16 [bh][s][64], V -> VT
//         bf16 [bh][64][s]).  MODE 1: plain fp32 out = acc + bias.
// Epilogue uses ONLY inlined intrinsics — libm sincosf/powf generated
// ~785 MB scratch traffic (R4).
// ---------------------------------------------------------------------------
template <int MODE>
__global__ __launch_bounds__(256) void mfma_gemm128_kernel(
    const short* __restrict__ A, const short* __restrict__ Bt,
    const float* __restrict__ bias, const int* __restrict__ layer_idx_p,
    short* __restrict__ Qb, short* __restrict__ Kb, short* __restrict__ VT,
    float* __restrict__ Out, int K, int Ncols)
{
  __shared__ short As[128 * 64];   // 16 KB
  __shared__ short Bs[64 * 64];    //  8 KB
  const int tid = threadIdx.x;
  const int w = tid >> 6, lane = tid & 63;
  const int c = lane & 15, g = lane >> 4;
  const int bm = blockIdx.y * 128, bn = blockIdx.x * 64;
  const int lr = lane >> 3;            // staging row 0..7
  const int gch = (lane & 7) ^ lr;     // swizzled global K-chunk index

  float4v acc[2][4];
#pragma unroll
  for (int i = 0; i < 2; ++i)
#pragma unroll
    for (int j = 0; j < 4; ++j) acc[i][j] = (float4v){0.f, 0.f, 0.f, 0.f};

  const short* Ag = A + (size_t)(bm + w * 32 + lr) * K + gch * 8;
  const short* Bg = Bt + (size_t)(bn + w * 16 + lr) * K + gch * 8;
  short* AsW = As + (w * 32) * 64;     // wave-uniform LDS stage base
  short* BsW = Bs + (w * 16) * 64;

  const int cl7 = c & 7;
  const short* aw = As + (w * 32 + c) * 64;
  const short* bwp = Bs + c * 64;

  for (int k0 = 0; k0 < K; k0 += 64) {
    async_copy16(AsW,        Ag + k0);
    async_copy16(AsW + 512,  Ag + k0 + (size_t)8 * K);
    async_copy16(AsW + 1024, Ag + k0 + (size_t)16 * K);
    async_copy16(AsW + 1536, Ag + k0 + (size_t)24 * K);
    async_copy16(BsW,        Bg + k0);
    async_copy16(BsW + 512,  Bg + k0 + (size_t)8 * K);
    __syncthreads();   // drains vmcnt -> staged data visible

    short8 af[2][2], bfr[4][2];
#pragma unroll
    for (int t = 0; t < 2; ++t) {
      const int slot = ((t * 4 + g) ^ cl7) * 8;
#pragma unroll
      for (int i = 0; i < 2; ++i) af[i][t] = *(const short8*)(aw + i * 16 * 64 + slot);
#pragma unroll
      for (int j = 0; j < 4; ++j) bfr[j][t] = *(const short8*)(bwp + j * 16 * 64 + slot);
    }
#pragma unroll
    for (int t = 0; t < 2; ++t)
#pragma unroll
      for (int i = 0; i < 2; ++i)
#pragma unroll
        for (int j = 0; j < 4; ++j)
          acc[i][j] = __builtin_amdgcn_mfma_f32_16x16x32_bf16(af[i][t], bfr[j][t], acc[i][j], 0, 0, 0);
    __syncthreads();   // protect LDS before next stage
  }

  const int wm = bm + w * 32;
  const int wn = bn;
  float bj[4];
#pragma unroll
  for (int j = 0; j < 4; ++j) bj[j] = bias[wn + j * 16 + c];

  if (MODE == 1) {
#pragma unroll
    for (int i = 0; i < 2; ++i)
#pragma unroll
      for (int j = 0; j < 4; ++j)
#pragma unroll
        for (int r = 0; r < 4; ++r)
          Out[(size_t)(wm + i * 16 + 4 * g + r) * Ncols + wn + j * 16 + c] =
              acc[i][j][r] + bj[j];
  } else {
    const int which = bn / ND;               // uniform per block (768%64==0)
    const int hd0 = wn - which * ND;         // 64-aligned
    const int h = hd0 >> 6;
    const int bidx = bm >> 11;
    const int srow = (bm & (NS - 1)) + w * 32;

    if (which == 2) {
      // V: no RoPE; VT[bh][d][s], short4 along s
#pragma unroll
      for (int j = 0; j < 4; ++j) {
        const int d = j * 16 + c;
        short* vbase = VT + ((size_t)(bidx * NH + h) * HD + d) * NS;
#pragma unroll
        for (int i = 0; i < 2; ++i) {
          short4v v4;
#pragma unroll
          for (int r = 0; r < 4; ++r) v4[r] = f2bf(acc[i][j][r] + bj[j]);
          *(short4v*)(vbase + srow + i * 16 + 4 * g) = v4;
        }
      }
    } else {
      const bool is_global = ((*layer_idx_p) % 3) == 0;
      const float theta = is_global ? 160000.0f : 10000.0f;
      const float nlt = -__logf(theta) * (1.0f / 64.0f);
      short* dst = which ? Kb : Qb;
      const bool oddc = (c & 1);
#pragma unroll
      for (int j = 0; j < 4; ++j) {
        const int d = j * 16 + c;
        const float freq = __expf((float)(d & ~1) * nlt);
#pragma unroll
        for (int i = 0; i < 2; ++i) {
#pragma unroll
          for (int r = 0; r < 4; ++r) {
            const float val = acc[i][j][r] + bj[j];
            const float partner = __shfl_xor(val, 1);
            const int s = srow + i * 16 + 4 * g + r;
            float sn, cs;
            __sincosf((float)s * freq, &sn, &cs);
            const float o = oddc ? (val * cs + partner * sn)
                                 : (val * cs - partner * sn);
            dst[((size_t)(bidx * NH + h) * NS + s) * HD + d] = f2bf(o);
          }
        }
      }
    }
  }
}

// ---------------------------------------------------------------------------
// MFMA banded flash attention (fixed-reference softmax: scores provably
// bounded, p = exp(s/8), masked -> exp(-1e30)=0; l reduced once in the
// epilogue — removes the online-softmax serial chain, R7).
// ---------------------------------------------------------------------------
__global__ __launch_bounds__(256) void attn_mfma_kernel(
    const short* __restrict__ Qb, const short* __restrict__ Kb,
    const short* __restrict__ VT, short* __restrict__ CTXb,
    const int* __restrict__ layer_idx_p)
{
  const int lane = threadIdx.x & 63;
  const int wv = threadIdx.x >> 6;
  const int c = lane & 15;
  const int g = lane >> 4;
  const int bh = blockIdx.x >> 5;
  const int qt = blockIdx.x & 31;
  const int b = bh / NH;
  const int h = bh - b * NH;
  const int q0 = qt * 64 + wv * 16;
  const bool is_global = ((*layer_idx_p) % 3) == 0;
  const size_t base = (size_t)bh * NS * HD;

  const short* qrow = Qb + base + (size_t)(q0 + c) * HD + g * 8;
  const short8 qf0 = *(const short8*)(qrow);
  const short8 qf1 = *(const short8*)(qrow + 32);

  float4v O0 = {0.f, 0.f, 0.f, 0.f}, O1 = O0, O2 = O0, O3 = O0;
  float lacc = 0.0f;
  const int q = q0 + c;

  const int lo = is_global ? 0 : q0 - 128;
  const int hi = is_global ? (NS - 1) : q0 + 143;

  for (int kt = lo; kt <= hi; kt += 32) {
    if (kt + 31 < 0 || kt >= NS) continue;

    const int k1c = min(max(kt + c, 0), NS - 1);
    const int k2c = min(max(kt + 16 + c, 0), NS - 1);
    const short* kr1 = Kb + base + (size_t)k1c * HD + g * 8;
    const short* kr2 = Kb + base + (size_t)k2c * HD + g * 8;
    const short8 kf10 = *(const short8*)kr1;
    const short8 kf11 = *(const short8*)(kr1 + 32);
    const short8 kf20 = *(const short8*)kr2;
    const short8 kf21 = *(const short8*)(kr2 + 32);
    float4v st1 = {0.f, 0.f, 0.f, 0.f}, st2 = {0.f, 0.f, 0.f, 0.f};
    st1 = __builtin_amdgcn_mfma_f32_16x16x32_bf16(kf10, qf0, st1, 0, 0, 0);
    st1 = __builtin_amdgcn_mfma_f32_16x16x32_bf16(kf11, qf1, st1, 0, 0, 0);
    st2 = __builtin_amdgcn_mfma_f32_16x16x32_bf16(kf20, qf0, st2, 0, 0, 0);
    st2 = __builtin_amdgcn_mfma_f32_16x16x32_bf16(kf21, qf1, st2, 0, 0, 0);

    float p1[4], p2[4];
#pragma unroll
    for (int r = 0; r < 4; ++r) {
      const int key1 = kt + 4 * g + r;
      const int key2 = key1 + 16;
      const bool v1 = (key1 >= 0) & (key1 < NS) &
                      (is_global | ((key1 - q <= WIN) & (q - key1 <= WIN)));
      const bool v2 = (key2 >= 0) & (key2 < NS) &
                      (is_global | ((key2 - q <= WIN) & (q - key2 <= WIN)));
      p1[r] = __expf(v1 ? st1[r] * 0.125f : -1e30f);
      p2[r] = __expf(v2 ? st2[r] * 0.125f : -1e30f);
      lacc += p1[r] + p2[r];
    }

    const int srcA = (2 * (g & 1)) * 16 + c;
    const int srcB = srcA + 16;
    short8 pf;
#pragma unroll
    for (int r = 0; r < 4; ++r) {
      const float f1a = __shfl(p1[r], srcA);
      const float f1b = __shfl(p1[r], srcB);
      const float f2a = __shfl(p2[r], srcA);
      const float f2b = __shfl(p2[r], srcB);
      pf[r]     = f2bf((g < 2) ? f1a : f2a);
      pf[4 + r] = f2bf((g < 2) ? f1b : f2b);
    }

    const int ks = min(max(kt + 8 * g, 0), NS - 8);
    const short* vrow = VT + base + (size_t)c * NS + ks;
    const short8 vf0 = *(const short8*)(vrow);
    const short8 vf1 = *(const short8*)(vrow + 16 * NS);
    const short8 vf2 = *(const short8*)(vrow + 32 * NS);
    const short8 vf3 = *(const short8*)(vrow + 48 * NS);
    O0 = __builtin_amdgcn_mfma_f32_16x16x32_bf16(vf0, pf, O0, 0, 0, 0);
    O1 = __builtin_amdgcn_mfma_f32_16x16x32_bf16(vf1, pf, O1, 0, 0, 0);
    O2 = __builtin_amdgcn_mfma_f32_16x16x32_bf16(vf2, pf, O2, 0, 0, 0);
    O3 = __builtin_amdgcn_mfma_f32_16x16x32_bf16(vf3, pf, O3, 0, 0, 0);
  }

  // epilogue: one cross-quad reduction of l, then scale+store
  lacc += __shfl_xor(lacc, 16);
  lacc += __shfl_xor(lacc, 32);
  const float inv = 1.0f / lacc;
  short* crow = CTXb + ((size_t)(b * NS + q) * NH + h) * HD;
#pragma unroll
  for (int r = 0; r < 4; ++r) {
    const int d = 4 * g + r;
    crow[d]      = f2bf(O0[r] * inv);
    crow[d + 16] = f2bf(O1[r] * inv);
    crow[d + 32] = f2bf(O2[r] * inv);
    crow[d + 48] = f2bf(O3[r] * inv);
  }
}

// ---------------------------------------------------------------------------
extern "C" void kernel_launch(void* const* d_in, const int* in_sizes, int n_in,
                              void* d_out, int out_size, void* d_ws, size_t ws_size,
                              hipStream_t stream) {
  const float* x    = (const float*)d_in[0];
  const float* Wqkv = (const float*)d_in[1];
  const float* bqkv = (const float*)d_in[2];
  const float* Wout = (const float*)d_in[3];
  const float* bout = (const float*)d_in[4];
  const int* layer_idx = (const int*)d_in[5];

  short* xb    = (short*)d_ws;                         // [4096][768]
  short* Wqkvt = xb + (size_t)NB * NS * ND;            // [2304][768]
  short* Woutt = Wqkvt + (size_t)ND * N_QKV;           // [768][768]
  short* Qb    = Woutt + (size_t)ND * ND;              // [bh][s][64]
  short* Kb    = Qb + (size_t)QKN;
  short* VT    = Kb + (size_t)QKN;                     // [bh][64][s]
  short* CTXb  = VT + (size_t)QKN;                     // [4096][768]
  // total: 18087936 shorts = 36.2 MB

  // phase 0: all preps in one dispatch (3072 cvt + 1728 + 576 transpose units)
  prep_kernel<<<5376, 256, 0, stream>>>(x, Wqkv, Wout, xb, Wqkvt, Woutt);

  // QKV GEMM + RoPE: M=4096, N=2304, K=768
  mfma_gemm128_kernel<0><<<dim3(N_QKV / 64, (NB * NS) / 128), 256, 0, stream>>>(
      xb, Wqkvt, bqkv, layer_idx, Qb, Kb, VT, nullptr, ND, N_QKV);

  attn_mfma_kernel<<<NB * NH * (NS / 64), 256, 0, stream>>>(Qb, Kb, VT, CTXb, layer_idx);

  // Out projection: M=4096, N=768, K=768
  mfma_gemm128_kernel<1><<<dim3(ND / 64, (NB * NS) / 128), 256, 0, stream>>>(
      CTXb, Woutt, bout, layer_idx, nullptr, nullptr, nullptr, (float*)d_out, ND, ND);
}

// Round 11
// 147.546 us; speedup vs baseline: 9.0721x; 1.0231x over previous
//
#include <hip/hip_runtime.h>
#include <hip/hip_bf16.h>
#include <math.h>

#define NB 2
#define NS 2048
#define ND 768
#define NH 12
#define HD 64
#define WIN 128
#define N_QKV 2304
#define QKN (NB * NH * NS * HD)   // 3145728

typedef __attribute__((ext_vector_type(8))) short short8;
typedef __attribute__((ext_vector_type(4))) short short4v;
typedef __attribute__((ext_vector_type(4))) float float4v;

static __device__ __forceinline__ short f2bf(float f) {
  __hip_bfloat16 h = __float2bfloat16(f);
  short s;
  __builtin_memcpy(&s, &h, 2);
  return s;
}

static __device__ __forceinline__ void async_copy16(void* lds, const void* g) {
  __builtin_amdgcn_global_load_lds(
      (const __attribute__((address_space(1))) unsigned int*)g,
      (__attribute__((address_space(3))) unsigned int*)(unsigned int)(unsigned long long)lds,
      16, 0, 0);
}

// ---------------------------------------------------------------------------
// Merged prep kernel: x cvt (3072 units) + Wqkv^T (1728) + Wout^T (576).
// ---------------------------------------------------------------------------
__global__ __launch_bounds__(256) void prep_kernel(
    const float* __restrict__ x, const float* __restrict__ Wqkv,
    const float* __restrict__ Wout, short* __restrict__ xb,
    short* __restrict__ Wqkvt, short* __restrict__ Woutt)
{
  __shared__ float t[32][33];
  const int u = blockIdx.x;
  const int tid = threadIdx.x;

  if (u < 3072) {
    const int i = u * 1024 + tid * 4;
    const float4 v = *(const float4*)(x + i);
    short4v o;
    o[0] = f2bf(v.x); o[1] = f2bf(v.y); o[2] = f2bf(v.z); o[3] = f2bf(v.w);
    *(short4v*)(xb + i) = o;
    return;
  }

  const bool isqkv = (u < 4800);
  const float* in = isqkv ? Wqkv : Wout;
  short* out = isqkv ? Wqkvt : Woutt;
  const int C = isqkv ? N_QKV : ND;       // in cols
  const int tt = u - (isqkv ? 3072 : 4800);
  const int nbx = C / 32;
  const int bx = (tt % nbx) * 32;         // col base
  const int by = (tt / nbx) * 32;         // row base
  const int tx = tid & 31, ty = tid >> 5; // ty 0..7
#pragma unroll
  for (int i = 0; i < 32; i += 8)
    t[ty + i][tx] = in[(size_t)(by + ty + i) * C + bx + tx];
  __syncthreads();
#pragma unroll
  for (int i = 0; i < 32; i += 8)
    out[(size_t)(bx + ty + i) * ND + by + tx] = f2bf(t[tx][ty + i]);
}

// ---------------------------------------------------------------------------
// MFMA GEMM: 128x64 tile, BK=64, 4 waves each 32x64 via 2x4 16x16x32 bf16
// frags, global_load_lds width-16 staging, XOR-swizzled K-chunk LDS slots.
// R10: 1-D grid + XCD-aware tile swizzle (id&7 = XCD heuristic): each XCD
// owns a contiguous m-slab (A slab + full Bt fit its 4 MB L2), converting
// ~340 MB of L3 re-reads into L2 hits.
// MODE 0: qkv epilogue (bias + RoPE -> Qb/Kb [bh][s][64], V -> VT
//         [bh][64][s]).  MODE 1: plain fp32 out = acc + bias.
// Intrinsics only in epilogue (libm caused ~785 MB scratch traffic, R4).
// ---------------------------------------------------------------------------
template <int MODE>
__global__ __launch_bounds__(256) void mfma_gemm128_kernel(
    const short* __restrict__ A, const short* __restrict__ Bt,
    const float* __restrict__ bias, const int* __restrict__ layer_idx_p,
    short* __restrict__ Qb, short* __restrict__ Kb, short* __restrict__ VT,
    float* __restrict__ Out, int K, int Ncols, int nTN, int mPerXcd)
{
  __shared__ short As[128 * 64];   // 16 KB
  __shared__ short Bs[64 * 64];    //  8 KB
  const int tid = threadIdx.x;
  const int w = tid >> 6, lane = tid & 63;
  const int c = lane & 15, g = lane >> 4;

  // XCD-aware swizzle: xcd = id&7 owns m-tiles [xcd*mPerXcd, ...+mPerXcd)
  const int id = blockIdx.x;
  const int xcd = id & 7;
  const int k = id >> 3;
  const int mt = xcd * mPerXcd + k / nTN;
  const int nt = k - (k / nTN) * nTN;
  const int bm = mt * 128, bn = nt * 64;

  const int lr = lane >> 3;            // staging row 0..7
  const int gch = (lane & 7) ^ lr;     // swizzled global K-chunk index

  float4v acc[2][4];
#pragma unroll
  for (int i = 0; i < 2; ++i)
#pragma unroll
    for (int j = 0; j < 4; ++j) acc[i][j] = (float4v){0.f, 0.f, 0.f, 0.f};

  const short* Ag = A + (size_t)(bm + w * 32 + lr) * K + gch * 8;
  const short* Bg = Bt + (size_t)(bn + w * 16 + lr) * K + gch * 8;
  short* AsW = As + (w * 32) * 64;     // wave-uniform LDS stage base
  short* BsW = Bs + (w * 16) * 64;

  const int cl7 = c & 7;
  const short* aw = As + (w * 32 + c) * 64;
  const short* bwp = Bs + c * 64;

  for (int k0 = 0; k0 < K; k0 += 64) {
    async_copy16(AsW,        Ag + k0);
    async_copy16(AsW + 512,  Ag + k0 + (size_t)8 * K);
    async_copy16(AsW + 1024, Ag + k0 + (size_t)16 * K);
    async_copy16(AsW + 1536, Ag + k0 + (size_t)24 * K);
    async_copy16(BsW,        Bg + k0);
    async_copy16(BsW + 512,  Bg + k0 + (size_t)8 * K);
    __syncthreads();   // drains vmcnt -> staged data visible

    short8 af[2][2], bfr[4][2];
#pragma unroll
    for (int t = 0; t < 2; ++t) {
      const int slot = ((t * 4 + g) ^ cl7) * 8;
#pragma unroll
      for (int i = 0; i < 2; ++i) af[i][t] = *(const short8*)(aw + i * 16 * 64 + slot);
#pragma unroll
      for (int j = 0; j < 4; ++j) bfr[j][t] = *(const short8*)(bwp + j * 16 * 64 + slot);
    }
#pragma unroll
    for (int t = 0; t < 2; ++t)
#pragma unroll
      for (int i = 0; i < 2; ++i)
#pragma unroll
        for (int j = 0; j < 4; ++j)
          acc[i][j] = __builtin_amdgcn_mfma_f32_16x16x32_bf16(af[i][t], bfr[j][t], acc[i][j], 0, 0, 0);
    __syncthreads();   // protect LDS before next stage
  }

  const int wm = bm + w * 32;
  const int wn = bn;
  float bj[4];
#pragma unroll
  for (int j = 0; j < 4; ++j) bj[j] = bias[wn + j * 16 + c];

  if (MODE == 1) {
#pragma unroll
    for (int i = 0; i < 2; ++i)
#pragma unroll
      for (int j = 0; j < 4; ++j)
#pragma unroll
        for (int r = 0; r < 4; ++r)
          Out[(size_t)(wm + i * 16 + 4 * g + r) * Ncols + wn + j * 16 + c] =
              acc[i][j][r] + bj[j];
  } else {
    const int which = bn / ND;               // uniform per block (768%64==0)
    const int hd0 = wn - which * ND;         // 64-aligned
    const int h = hd0 >> 6;
    const int bidx = bm >> 11;
    const int srow = (bm & (NS - 1)) + w * 32;

    if (which == 2) {
      // V: no RoPE; VT[bh][d][s], short4 along s
#pragma unroll
      for (int j = 0; j < 4; ++j) {
        const int d = j * 16 + c;
        short* vbase = VT + ((size_t)(bidx * NH + h) * HD + d) * NS;
#pragma unroll
        for (int i = 0; i < 2; ++i) {
          short4v v4;
#pragma unroll
          for (int r = 0; r < 4; ++r) v4[r] = f2bf(acc[i][j][r] + bj[j]);
          *(short4v*)(vbase + srow + i * 16 + 4 * g) = v4;
        }
      }
    } else {
      const bool is_global = ((*layer_idx_p) % 3) == 0;
      const float theta = is_global ? 160000.0f : 10000.0f;
      const float nlt = -__logf(theta) * (1.0f / 64.0f);
      short* dst = which ? Kb : Qb;
      const bool oddc = (c & 1);
#pragma unroll
      for (int j = 0; j < 4; ++j) {
        const int d = j * 16 + c;
        const float freq = __expf((float)(d & ~1) * nlt);
#pragma unroll
        for (int i = 0; i < 2; ++i) {
#pragma unroll
          for (int r = 0; r < 4; ++r) {
            const float val = acc[i][j][r] + bj[j];
            const float partner = __shfl_xor(val, 1);
            const int s = srow + i * 16 + 4 * g + r;
            float sn, cs;
            __sincosf((float)s * freq, &sn, &cs);
            const float o = oddc ? (val * cs + partner * sn)
                                 : (val * cs - partner * sn);
            dst[((size_t)(bidx * NH + h) * NS + s) * HD + d] = f2bf(o);
          }
        }
      }
    }
  }
}

// ---------------------------------------------------------------------------
// MFMA banded flash attention (fixed-reference softmax, R7). R10: XCD-aware
// swizzle — each XCD owns 3 heads (K+V slab 1.5 MB -> L2-resident).
// ---------------------------------------------------------------------------
__global__ __launch_bounds__(256) void attn_mfma_kernel(
    const short* __restrict__ Qb, const short* __restrict__ Kb,
    const short* __restrict__ VT, short* __restrict__ CTXb,
    const int* __restrict__ layer_idx_p)
{
  const int lane = threadIdx.x & 63;
  const int wv = threadIdx.x >> 6;
  const int c = lane & 15;
  const int g = lane >> 4;

  // swizzle: xcd = id&7 owns bh in [xcd*3, xcd*3+3)
  const int id = blockIdx.x;
  const int xcd = id & 7;
  const int k = id >> 3;               // 0..95
  const int bh = xcd * 3 + (k >> 5);
  const int qt = k & 31;

  const int b = bh / NH;
  const int h = bh - b * NH;
  const int q0 = qt * 64 + wv * 16;
  const bool is_global = ((*layer_idx_p) % 3) == 0;
  const size_t base = (size_t)bh * NS * HD;

  const short* qrow = Qb + base + (size_t)(q0 + c) * HD + g * 8;
  const short8 qf0 = *(const short8*)(qrow);
  const short8 qf1 = *(const short8*)(qrow + 32);

  float4v O0 = {0.f, 0.f, 0.f, 0.f}, O1 = O0, O2 = O0, O3 = O0;
  float lacc = 0.0f;
  const int q = q0 + c;

  const int lo = is_global ? 0 : q0 - 128;
  const int hi = is_global ? (NS - 1) : q0 + 143;

  for (int kt = lo; kt <= hi; kt += 32) {
    if (kt + 31 < 0 || kt >= NS) continue;

    const int k1c = min(max(kt + c, 0), NS - 1);
    const int k2c = min(max(kt + 16 + c, 0), NS - 1);
    const short* kr1 = Kb + base + (size_t)k1c * HD + g * 8;
    const short* kr2 = Kb + base + (size_t)k2c * HD + g * 8;
    const short8 kf10 = *(const short8*)kr1;
    const short8 kf11 = *(const short8*)(kr1 + 32);
    const short8 kf20 = *(const short8*)kr2;
    const short8 kf21 = *(const short8*)(kr2 + 32);
    float4v st1 = {0.f, 0.f, 0.f, 0.f}, st2 = {0.f, 0.f, 0.f, 0.f};
    st1 = __builtin_amdgcn_mfma_f32_16x16x32_bf16(kf10, qf0, st1, 0, 0, 0);
    st1 = __builtin_amdgcn_mfma_f32_16x16x32_bf16(kf11, qf1, st1, 0, 0, 0);
    st2 = __builtin_amdgcn_mfma_f32_16x16x32_bf16(kf20, qf0, st2, 0, 0, 0);
    st2 = __builtin_amdgcn_mfma_f32_16x16x32_bf16(kf21, qf1, st2, 0, 0, 0);

    float p1[4], p2[4];
#pragma unroll
    for (int r = 0; r < 4; ++r) {
      const int key1 = kt + 4 * g + r;
      const int key2 = key1 + 16;
      const bool v1 = (key1 >= 0) & (key1 < NS) &
                      (is_global | ((key1 - q <= WIN) & (q - key1 <= WIN)));
      const bool v2 = (key2 >= 0) & (key2 < NS) &
                      (is_global | ((key2 - q <= WIN) & (q - key2 <= WIN)));
      p1[r] = __expf(v1 ? st1[r] * 0.125f : -1e30f);
      p2[r] = __expf(v2 ? st2[r] * 0.125f : -1e30f);
      lacc += p1[r] + p2[r];
    }

    const int srcA = (2 * (g & 1)) * 16 + c;
    const int srcB = srcA + 16;
    short8 pf;
#pragma unroll
    for (int r = 0; r < 4; ++r) {
      const float f1a = __shfl(p1[r], srcA);
      const float f1b = __shfl(p1[r], srcB);
      const float f2a = __shfl(p2[r], srcA);
      const float f2b = __shfl(p2[r], srcB);
      pf[r]     = f2bf((g < 2) ? f1a : f2a);
      pf[4 + r] = f2bf((g < 2) ? f1b : f2b);
    }

    const int ks = min(max(kt + 8 * g, 0), NS - 8);
    const short* vrow = VT + base + (size_t)c * NS + ks;
    const short8 vf0 = *(const short8*)(vrow);
    const short8 vf1 = *(const short8*)(vrow + 16 * NS);
    const short8 vf2 = *(const short8*)(vrow + 32 * NS);
    const short8 vf3 = *(const short8*)(vrow + 48 * NS);
    O0 = __builtin_amdgcn_mfma_f32_16x16x32_bf16(vf0, pf, O0, 0, 0, 0);
    O1 = __builtin_amdgcn_mfma_f32_16x16x32_bf16(vf1, pf, O1, 0, 0, 0);
    O2 = __builtin_amdgcn_mfma_f32_16x16x32_bf16(vf2, pf, O2, 0, 0, 0);
    O3 = __builtin_amdgcn_mfma_f32_16x16x32_bf16(vf3, pf, O3, 0, 0, 0);
  }

  // epilogue: one cross-quad reduction of l, then scale+store
  lacc += __shfl_xor(lacc, 16);
  lacc += __shfl_xor(lacc, 32);
  const float inv = 1.0f / lacc;
  short* crow = CTXb + ((size_t)(b * NS + q) * NH + h) * HD;
#pragma unroll
  for (int r = 0; r < 4; ++r) {
    const int d = 4 * g + r;
    crow[d]      = f2bf(O0[r] * inv);
    crow[d + 16] = f2bf(O1[r] * inv);
    crow[d + 32] = f2bf(O2[r] * inv);
    crow[d + 48] = f2bf(O3[r] * inv);
  }
}

// ---------------------------------------------------------------------------
extern "C" void kernel_launch(void* const* d_in, const int* in_sizes, int n_in,
                              void* d_out, int out_size, void* d_ws, size_t ws_size,
                              hipStream_t stream) {
  const float* x    = (const float*)d_in[0];
  const float* Wqkv = (const float*)d_in[1];
  const float* bqkv = (const float*)d_in[2];
  const float* Wout = (const float*)d_in[3];
  const float* bout = (const float*)d_in[4];
  const int* layer_idx = (const int*)d_in[5];

  short* xb    = (short*)d_ws;                         // [4096][768]
  short* Wqkvt = xb + (size_t)NB * NS * ND;            // [2304][768]
  short* Woutt = Wqkvt + (size_t)ND * N_QKV;           // [768][768]
  short* Qb    = Woutt + (size_t)ND * ND;              // [bh][s][64]
  short* Kb    = Qb + (size_t)QKN;
  short* VT    = Kb + (size_t)QKN;                     // [bh][64][s]
  short* CTXb  = VT + (size_t)QKN;                     // [4096][768]
  // total: 18087936 shorts = 36.2 MB

  // phase 0: all preps in one dispatch
  prep_kernel<<<5376, 256, 0, stream>>>(x, Wqkv, Wout, xb, Wqkvt, Woutt);

  // QKV GEMM + RoPE: M=4096, N=2304, K=768. 32 m-tiles x 36 n-tiles = 1152.
  mfma_gemm128_kernel<0><<<1152, 256, 0, stream>>>(
      xb, Wqkvt, bqkv, layer_idx, Qb, Kb, VT, nullptr, ND, N_QKV, 36, 4);

  attn_mfma_kernel<<<NB * NH * (NS / 64), 256, 0, stream>>>(Qb, Kb, VT, CTXb, layer_idx);

  // Out projection: M=4096, N=768, K=768. 32 m-tiles x 12 n-tiles = 384.
  mfma_gemm128_kernel<1><<<384, 256, 0, stream>>>(
      CTXb, Woutt, bout, layer_idx, nullptr, nullptr, nullptr, (float*)d_out, ND, ND, 12, 4);
}